// Round 17
// baseline (402.993 us; speedup 1.0000x reference)
//
#include <hip/hip_runtime.h>
#include <cstdint>
#include <cstddef>

#define B_    16
#define T_    1024
#define NF_   64
#define D_    128
#define H_    4
#define DFF_  512
#define M_    16384   // B_*T_

#define OUT_SP     0
#define OUT_REG    65536
#define OUT_PROBS  81920
#define OUT_H      147456
#define OUT_FS     2244608

#define LOG2E 1.4426950408889634f
#define SWZ(x) (((x) & 3) ^ (((x) >> 2) & 3))

typedef float f32x4 __attribute__((ext_vector_type(4)));
typedef short bf16x8 __attribute__((ext_vector_type(8)));
typedef unsigned short u16;
typedef unsigned int u32;

// native 2^x (v_exp_f32, 1ulp)
__device__ __forceinline__ float fexp2(float x) {
  float r;
  asm("v_exp_f32 %0, %1" : "=v"(r) : "v"(x));
  return r;
}
__device__ __forceinline__ float b2f(u16 b) {
  union { u32 u; float f; } x; x.u = ((u32)b) << 16; return x.f;
}
// HW bf16 conversions
__device__ __forceinline__ void bsplit(float v, u16& h, u16& l) {
  __bf16 hb = (__bf16)v;
  float rec = (float)hb;
  __bf16 lb = (__bf16)(v - rec);
  h = __builtin_bit_cast(u16, hb);
  l = __builtin_bit_cast(u16, lb);
}
__device__ __forceinline__ u16 bhi(float v) {
  __bf16 hb = (__bf16)v;
  return __builtin_bit_cast(u16, hb);
}
__device__ __forceinline__ void gload16(const void* g, void* l) {
  __builtin_amdgcn_global_load_lds((const __attribute__((address_space(1))) void*)g,
                                   (__attribute__((address_space(3))) void*)l, 16, 0, 0);
}
__device__ __forceinline__ f32x4 mfma_bf16(bf16x8 a, bf16x8 b, f32x4 c) {
  return __builtin_amdgcn_mfma_f32_16x16x32_bf16(a, b, c, 0, 0, 0);
}

// DPP helpers: pure-VALU cross-lane (no LDS pipe)
template <int CTRL>
__device__ __forceinline__ float fdpp(float x) {
  int i = __builtin_bit_cast(int, x);
  i = __builtin_amdgcn_mov_dpp(i, CTRL, 0xf, 0xf, true);
  return __builtin_bit_cast(float, i);
}
__device__ __forceinline__ float red16_sum(float x) {
  x += fdpp<0xB1>(x);
  x += fdpp<0x4E>(x);
  x += fdpp<0x124>(x);
  x += fdpp<0x128>(x);
  return x;
}
__device__ __forceinline__ float qb0(float x) { return fdpp<0x00>(x); }
__device__ __forceinline__ float qb1(float x) { return fdpp<0x55>(x); }
__device__ __forceinline__ float qb2(float x) { return fdpp<0xAA>(x); }
__device__ __forceinline__ float qb3(float x) { return fdpp<0xFF>(x); }

// ---------------- fused split (vec4) of 6 fp32 tensors + centroid normalization ----------------
__global__ __launch_bounds__(256)
void k_split6(const float* __restrict__ s0, u16* h0, u16* l0,
              const float* __restrict__ s1, u16* h1, u16* l1,
              const float* __restrict__ s2, u16* h2, u16* l2,
              const float* __restrict__ s3, u16* h3, u16* l3,
              const float* __restrict__ s4, u16* h4, u16* l4,
              const float* __restrict__ s5, u16* h5, u16* l5,
              const float* __restrict__ cent, float* __restrict__ cn) {
  if (blockIdx.x == 1800) {           // folded k_cnorm (one wave)
    const int lane = threadIdx.x;
    if (lane < 64) {
      for (int r = 0; r < 4; ++r) {
        float2 v = *(const float2*)&cent[r * 128 + lane * 2];
        float ss = v.x * v.x + v.y * v.y;
#pragma unroll
        for (int d = 1; d < 64; d <<= 1) ss += __shfl_xor(ss, d, 64);
        float nrm = fmaxf(sqrtf(ss), 1e-12f);
        float2 o; o.x = v.x / nrm; o.y = v.y / nrm;
        *(float2*)&cn[r * 128 + lane * 2] = o;
      }
    }
    return;
  }
  int i = blockIdx.x * 256 + threadIdx.x;   // vec4 index, 0..460799
  const float* s; u16 *h, *l; int j;
  if      (i < 262144) { s = s0; h = h0; l = l0; j = i; }
  else if (i < 264192) { s = s1; h = h1; l = l1; j = i - 262144; }
  else if (i < 313344) { s = s2; h = h2; l = l2; j = i - 264192; }
  else if (i < 329728) { s = s3; h = h3; l = l3; j = i - 313344; }
  else if (i < 395264) { s = s4; h = h4; l = l4; j = i - 329728; }
  else                 { s = s5; h = h5; l = l5; j = i - 395264; }
  float4 v = *(const float4*)&s[(size_t)j * 4];
  ushort4 hh, ll;
  bsplit(v.x, hh.x, ll.x);
  bsplit(v.y, hh.y, ll.y);
  bsplit(v.z, hh.z, ll.z);
  bsplit(v.w, hh.w, ll.w);
  *(ushort4*)&h[(size_t)j * 4] = hh;
  *(ushort4*)&l[(size_t)j * 4] = ll;
}

// ---------------- split-bf16 GEMM, 128x128 tile, double-buffered staging ----------------
template <int RELU, int OUTMODE, int VT>
__global__ __launch_bounds__(256)
void k_gemm(const u16* __restrict__ Ahi, const u16* __restrict__ Alo,
            const u16* __restrict__ Whi, const u16* __restrict__ Wlo,
            const float* __restrict__ bias,
            float* __restrict__ Cf, u16* __restrict__ Chi, u16* __restrict__ Clo,
            u16* __restrict__ vth, u16* __restrict__ vtl,
            int N, int K) {
  __shared__ u16 lA[2][2][128 * 32];
  __shared__ u16 lB[2][2][128 * 32];
  const int tid = threadIdx.x;
  const int wv = tid >> 6, lane = tid & 63;
  const int lo16 = lane & 15, hi2 = lane >> 4;
  const int m0 = blockIdx.x * 128, n0 = blockIdx.y * 128;
  const int ar = tid >> 2;
  const int slot = tid & 3;
  const int ac = ((slot ^ SWZ(ar)) * 8);
  const int dst = ar * 32 + slot * 8;
  const int aslot = ((hi2 ^ SWZ(lo16)) * 8);

  f32x4 acc[2][8];
#pragma unroll
  for (int i = 0; i < 2; ++i)
#pragma unroll
    for (int j = 0; j < 8; ++j) acc[i][j] = (f32x4){0.f, 0.f, 0.f, 0.f};

  auto stage = [&](int buf, int k0) {
    gload16(Ahi + (size_t)(m0 + ar) * K + k0 + ac,      &lA[buf][0][dst]);
    gload16(Ahi + (size_t)(m0 + 64 + ar) * K + k0 + ac, &lA[buf][0][64 * 32 + dst]);
    gload16(Alo + (size_t)(m0 + ar) * K + k0 + ac,      &lA[buf][1][dst]);
    gload16(Alo + (size_t)(m0 + 64 + ar) * K + k0 + ac, &lA[buf][1][64 * 32 + dst]);
    gload16(Whi + (size_t)(n0 + ar) * K + k0 + ac,      &lB[buf][0][dst]);
    gload16(Whi + (size_t)(n0 + 64 + ar) * K + k0 + ac, &lB[buf][0][64 * 32 + dst]);
    gload16(Wlo + (size_t)(n0 + ar) * K + k0 + ac,      &lB[buf][1][dst]);
    gload16(Wlo + (size_t)(n0 + 64 + ar) * K + k0 + ac, &lB[buf][1][64 * 32 + dst]);
  };
  const int nks = K >> 5;
  stage(0, 0);
  for (int ks = 0; ks < nks; ++ks) {
    const int cur = ks & 1;
    if (ks + 1 < nks) {
      stage(cur ^ 1, (ks + 1) * 32);
      asm volatile("s_waitcnt vmcnt(8)" ::: "memory");
    } else {
      asm volatile("s_waitcnt vmcnt(0)" ::: "memory");
    }
    __builtin_amdgcn_s_barrier();

    bf16x8 af[2][2];
#pragma unroll
    for (int rt = 0; rt < 2; ++rt)
#pragma unroll
      for (int p = 0; p < 2; ++p)
        af[rt][p] = *(const bf16x8*)&lA[cur][p][(wv * 32 + rt * 16 + lo16) * 32 + aslot];
#pragma unroll
    for (int ct = 0; ct < 8; ++ct) {
      bf16x8 bf0 = *(const bf16x8*)&lB[cur][0][(ct * 16 + lo16) * 32 + aslot];
      bf16x8 bf1 = *(const bf16x8*)&lB[cur][1][(ct * 16 + lo16) * 32 + aslot];
#pragma unroll
      for (int rt = 0; rt < 2; ++rt) {
        acc[rt][ct] = mfma_bf16(af[rt][0], bf0, acc[rt][ct]);
        acc[rt][ct] = mfma_bf16(af[rt][0], bf1, acc[rt][ct]);
        acc[rt][ct] = mfma_bf16(af[rt][1], bf0, acc[rt][ct]);
      }
    }
    __builtin_amdgcn_s_barrier();
  }

  if (VT && n0 >= 256) {
#pragma unroll
    for (int rt = 0; rt < 2; ++rt)
#pragma unroll
      for (int ct = 0; ct < 8; ++ct) {
        const int col = n0 + ct * 16 + lo16;
        const float bc = bias[col];
        const int cv = col - 256;
        const int hh = cv >> 5, d = cv & 31;
        const int row0 = m0 + wv * 32 + rt * 16 + hi2 * 4;
        const int b = row0 >> 10, t0 = row0 & 1023;
        ushort4 sh, sl;
#pragma unroll
        for (int r = 0; r < 4; ++r) {
          float v = acc[rt][ct][r] + bc;
          u16 hbb, lbb;
          bsplit(v, hbb, lbb);
          ((u16*)&sh)[r] = hbb;
          ((u16*)&sl)[r] = lbb;
        }
        const size_t o = ((size_t)((b * 4 + hh) * 32 + d)) * 1024 + t0;
        *(ushort4*)&vth[o] = sh;
        *(ushort4*)&vtl[o] = sl;
      }
    return;
  }

#pragma unroll
  for (int rt = 0; rt < 2; ++rt)
#pragma unroll
    for (int ct = 0; ct < 8; ++ct) {
      const int col = n0 + ct * 16 + lo16;
      const float bc = bias[col];
#pragma unroll
      for (int r = 0; r < 4; ++r) {
        const int row = m0 + wv * 32 + rt * 16 + hi2 * 4 + r;
        float v = acc[rt][ct][r] + bc;
        if (RELU) v = fmaxf(v, 0.f);
        const size_t idx = (size_t)row * N + col;
        if (OUTMODE & 1) Cf[idx] = v;
        if (OUTMODE & 2) {
          u16 hb, lb;
          bsplit(v, hb, lb);
          Chi[idx] = hb;
          Clo[idx] = lb;
        }
      }
    }
}

// ---------------- fused GEMM (N=128) + residual + LayerNorm, BM=32, 2 blocks/CU ----------------
template <int KSTEPS>
__global__ __launch_bounds__(256)
void k_gemm_ln(const u16* __restrict__ Ahi, const u16* __restrict__ Alo,
               const u16* __restrict__ Whi, const u16* __restrict__ Wlo,
               const float* __restrict__ bias, const float* __restrict__ hres,
               const float* __restrict__ lnw, const float* __restrict__ lnb,
               float* __restrict__ hf, u16* __restrict__ hhi, u16* __restrict__ hlo) {
  __shared__ u16 lA[2][2][32 * 32];
  __shared__ u16 lB[2][2][128 * 32];
  __shared__ float part[2][32][2];
  const int tid = threadIdx.x;
  const int wv = tid >> 6, lane = tid & 63;
  const int lo16 = lane & 15, hi2 = lane >> 4;
  const int rg = wv & 1, ch = wv >> 1;
  const int m0 = blockIdx.x * 32;
  const int K = KSTEPS * 32;
  const int ap = tid >> 7;
  const int arow = (tid & 127) >> 2;
  const int aslt = tid & 3;
  const int aac = ((aslt ^ SWZ(arow)) * 8);
  const int br = tid >> 2;
  const int bac = ((aslt ^ SWZ(br)) * 8);
  const int bdst = br * 32 + aslt * 8;
  const int rslot = ((hi2 ^ SWZ(lo16)) * 8);

  f32x4 acc[4];
#pragma unroll
  for (int j = 0; j < 4; ++j) acc[j] = (f32x4){0.f, 0.f, 0.f, 0.f};

  auto stage = [&](int buf, int k0) {
    const u16* Asrc = ap ? Alo : Ahi;
    gload16(Asrc + (size_t)(m0 + arow) * K + k0 + aac, &lA[buf][ap][(tid & 127) * 8]);
    gload16(Whi + (size_t)br * K + k0 + bac,        &lB[buf][0][bdst]);
    gload16(Whi + (size_t)(64 + br) * K + k0 + bac, &lB[buf][0][64 * 32 + bdst]);
    gload16(Wlo + (size_t)br * K + k0 + bac,        &lB[buf][1][bdst]);
    gload16(Wlo + (size_t)(64 + br) * K + k0 + bac, &lB[buf][1][64 * 32 + bdst]);
  };
  stage(0, 0);
  for (int ks = 0; ks < KSTEPS; ++ks) {
    const int cur = ks & 1;
    if (ks + 1 < KSTEPS) {
      stage(cur ^ 1, (ks + 1) * 32);
      asm volatile("s_waitcnt vmcnt(5)" ::: "memory");
    } else {
      asm volatile("s_waitcnt vmcnt(0)" ::: "memory");
    }
    __builtin_amdgcn_s_barrier();

    bf16x8 af0 = *(const bf16x8*)&lA[cur][0][(rg * 16 + lo16) * 32 + rslot];
    bf16x8 af1 = *(const bf16x8*)&lA[cur][1][(rg * 16 + lo16) * 32 + rslot];
#pragma unroll
    for (int ct2 = 0; ct2 < 4; ++ct2) {
      const int ct = ch * 4 + ct2;
      bf16x8 bf0 = *(const bf16x8*)&lB[cur][0][(ct * 16 + lo16) * 32 + rslot];
      bf16x8 bf1 = *(const bf16x8*)&lB[cur][1][(ct * 16 + lo16) * 32 + rslot];
      acc[ct2] = mfma_bf16(af0, bf0, acc[ct2]);
      acc[ct2] = mfma_bf16(af0, bf1, acc[ct2]);
      acc[ct2] = mfma_bf16(af1, bf0, acc[ct2]);
    }
    __builtin_amdgcn_s_barrier();
  }

  float w4[4], b4[4], bi4[4];
#pragma unroll
  for (int ct2 = 0; ct2 < 4; ++ct2) {
    const int col = ch * 64 + ct2 * 16 + lo16;
    w4[ct2] = lnw[col]; b4[ct2] = lnb[col]; bi4[ct2] = bias[col];
  }
  float vals[4][4];
#pragma unroll
  for (int r = 0; r < 4; ++r) {
    const int row = m0 + rg * 16 + hi2 * 4 + r;
    float sm = 0.f, sq = 0.f;
#pragma unroll
    for (int ct2 = 0; ct2 < 4; ++ct2) {
      float v = acc[ct2][r] + bi4[ct2] +
                hres[(size_t)row * 128 + ch * 64 + ct2 * 16 + lo16];
      vals[r][ct2] = v; sm += v; sq += v * v;
    }
    sm = red16_sum(sm);
    sq = red16_sum(sq);
    if (lo16 == 0) {
      part[ch][rg * 16 + hi2 * 4 + r][0] = sm;
      part[ch][rg * 16 + hi2 * 4 + r][1] = sq;
    }
  }
  __syncthreads();
#pragma unroll
  for (int r = 0; r < 4; ++r) {
    const int row = m0 + rg * 16 + hi2 * 4 + r;
    const int r32 = rg * 16 + hi2 * 4 + r;
    const float smT = part[0][r32][0] + part[1][r32][0];
    const float sqT = part[0][r32][1] + part[1][r32][1];
    const float mn = smT * (1.f / 128.f);
    const float inv = rsqrtf(sqT * (1.f / 128.f) - mn * mn + 1e-5f);
#pragma unroll
    for (int ct2 = 0; ct2 < 4; ++ct2) {
      float y = (vals[r][ct2] - mn) * inv * w4[ct2] + b4[ct2];
      const size_t idx = (size_t)row * 128 + ch * 64 + ct2 * 16 + lo16;
      hf[idx] = y;
      u16 hb, lb;
      bsplit(y, hb, lb);
      hhi[idx] = hb;
      hlo[idx] = lb;
    }
  }
}

// ---------------- flash attention: 512 threads / 128 q-rows per block,
//                  K/V staged once for 8 waves, P stored as bf16-hi ONLY ----------------
__global__ __launch_bounds__(512)
void k_attn(const u16* __restrict__ qkh, const u16* __restrict__ qkl,
            const u16* __restrict__ vth, const u16* __restrict__ vtl,
            u16* __restrict__ ohi, u16* __restrict__ olo) {
  __shared__ u16 lK[2][2][64 * 32];
  __shared__ u16 lV[2][2][32 * 64];
  __shared__ u16 lP[8][16 * 72];

  const int tid = threadIdx.x;
  const int wv = tid >> 6, lane = tid & 63;
  const int lo16 = lane & 15, hi2 = lane >> 4;
  const int bid = blockIdx.x;          // 0..511
  const int xcd = bid & 7, g = bid >> 3;
  const int bh = xcd * 8 + (g & 7);
  const int qp = g >> 3;               // 0..7: 128-row q block
  const int b = bh >> 2, h = bh & 3;
  const int st256 = tid & 255;
  const int ar = st256 >> 2, slot = st256 & 3;
  const int kac = ((slot ^ SWZ(ar)) * 8);
  const int kdst = ar * 32 + slot * 8;
  const int vrow = st256 >> 3, vslot = st256 & 7;
  const int vac = ((vslot ^ (vrow & 7)) * 8);
  const bool isK = tid < 256;

  const int qrow = qp * 128 + wv * 16 + lo16;
  const size_t qoff = ((size_t)b * T_ + qrow) * 384 + h * 32 + hi2 * 8;
  bf16x8 qf0 = *(const bf16x8*)&qkh[qoff];
  bf16x8 qf1 = *(const bf16x8*)&qkl[qoff];

  bf16x8 onesf;
#pragma unroll
  for (int j = 0; j < 8; ++j) onesf[j] = (short)0x3F80;

  auto stage = [&](int buf, int kt) {
    if (isK) {
      const size_t krow0 = (size_t)b * T_ + kt * 64;
      gload16(qkh + (krow0 + ar) * 384 + 128 + h * 32 + kac, &lK[buf][0][kdst]);
      gload16(qkl + (krow0 + ar) * 384 + 128 + h * 32 + kac, &lK[buf][1][kdst]);
    } else {
      const size_t vsrc = ((size_t)bh * 32 + vrow) * T_ + kt * 64 + vac;
      gload16(vth + vsrc, &lV[buf][0][vrow * 64 + vslot * 8]);
      gload16(vtl + vsrc, &lV[buf][1][vrow * 64 + vslot * 8]);
    }
  };

  u16* lPp = &lP[wv][0];
  f32x4 oacc[2];
  oacc[0] = (f32x4){0.f, 0.f, 0.f, 0.f};
  oacc[1] = (f32x4){0.f, 0.f, 0.f, 0.f};
  f32x4 lracc = (f32x4){0.f, 0.f, 0.f, 0.f};
  const float cs = 0.17677669529663687f * LOG2E;
  const int kso = ((hi2 ^ SWZ(lo16)) * 8);

  stage(0, 0);
  asm volatile("s_waitcnt vmcnt(0)" ::: "memory");
  __builtin_amdgcn_s_barrier();

  for (int kt = 0; kt < 16; ++kt) {
    const int cur = kt & 1;
    if (kt < 15) stage(cur ^ 1, kt + 1);

    f32x4 s[4];
#pragma unroll
    for (int ct = 0; ct < 4; ++ct) {
      bf16x8 kf0 = *(const bf16x8*)&lK[cur][0][(ct * 16 + lo16) * 32 + kso];
      bf16x8 kf1 = *(const bf16x8*)&lK[cur][1][(ct * 16 + lo16) * 32 + kso];
      f32x4 z = (f32x4){0.f, 0.f, 0.f, 0.f};
      z = mfma_bf16(qf0, kf0, z);
      z = mfma_bf16(qf0, kf1, z);
      z = mfma_bf16(qf1, kf0, z);
      s[ct] = z;
    }
#pragma unroll
    for (int r = 0; r < 4; ++r) {
      float p0 = fexp2(s[0][r] * cs), p1 = fexp2(s[1][r] * cs);
      float p2 = fexp2(s[2][r] * cs), p3 = fexp2(s[3][r] * cs);
      const int prow = hi2 * 4 + r;
      lPp[prow * 72 + 0 * 16 + lo16] = bhi(p0);
      lPp[prow * 72 + 1 * 16 + lo16] = bhi(p1);
      lPp[prow * 72 + 2 * 16 + lo16] = bhi(p2);
      lPp[prow * 72 + 3 * 16 + lo16] = bhi(p3);
    }
    asm volatile("s_waitcnt lgkmcnt(0)" ::: "memory");
    __builtin_amdgcn_sched_barrier(0);
#pragma unroll
    for (int c = 0; c < 2; ++c) {
      bf16x8 ph = *(const bf16x8*)&lPp[lo16 * 72 + c * 32 + hi2 * 8];
      lracc = mfma_bf16(ph, onesf, lracc);
#pragma unroll
      for (int ct2 = 0; ct2 < 2; ++ct2) {
        const int d = ct2 * 16 + lo16;
        const int vso = (((c * 4 + hi2) ^ (lo16 & 7)) * 8);
        bf16x8 vf0 = *(const bf16x8*)&lV[cur][0][d * 64 + vso];
        bf16x8 vf1 = *(const bf16x8*)&lV[cur][1][d * 64 + vso];
        oacc[ct2] = mfma_bf16(ph, vf0, oacc[ct2]);
        oacc[ct2] = mfma_bf16(ph, vf1, oacc[ct2]);
      }
    }
    if (kt < 15) {
      asm volatile("s_waitcnt vmcnt(0)" ::: "memory");
      __builtin_amdgcn_s_barrier();
    }
  }
#pragma unroll
  for (int ct2 = 0; ct2 < 2; ++ct2)
#pragma unroll
    for (int r = 0; r < 4; ++r) {
      float v = oacc[ct2][r] * __builtin_amdgcn_rcpf(lracc[r]);
      const int t = qp * 128 + wv * 16 + hi2 * 4 + r;
      const size_t idx = ((size_t)b * T_ + t) * D_ + h * 32 + ct2 * 16 + lo16;
      u16 hb, lb;
      bsplit(v, hb, lb);
      ohi[idx] = hb;
      olo[idx] = lb;
    }
}

// ---------------- head: final LN -> h out, cosine logits -> probs + GRU gi precompute ----------------
__global__ __launch_bounds__(256)
void k_head(const float* __restrict__ hin, const float* __restrict__ w,
            const float* __restrict__ bws, const float* __restrict__ cn,
            const float* __restrict__ temp,
            const float* __restrict__ wih, const float* __restrict__ bih,
            const float* __restrict__ bhh,
            float4* __restrict__ g4, float* __restrict__ out) {
  const int row = blockIdx.x * 4 + (threadIdx.x >> 6);
  const int lane = threadIdx.x & 63;
  const size_t base = (size_t)row * D_ + lane * 2;
  float2 x = *(const float2*)(hin + base);
  float s = x.x + x.y;
#pragma unroll
  for (int d2 = 1; d2 < 64; d2 <<= 1) s += __shfl_xor(s, d2, 64);
  float m = s * (1.f / 128.f);
  float dx = x.x - m, dy = x.y - m;
  float q = dx * dx + dy * dy;
#pragma unroll
  for (int d2 = 1; d2 < 64; d2 <<= 1) q += __shfl_xor(q, d2, 64);
  float inv = rsqrtf(q * (1.f / 128.f) + 1e-5f);
  float2 ww = *(const float2*)(w + lane * 2);
  float2 bb = *(const float2*)(bws + lane * 2);
  float y0 = dx * inv * ww.x + bb.x;
  float y1 = dy * inv * ww.y + bb.y;
  float2 yo; yo.x = y0; yo.y = y1;
  *(float2*)(out + OUT_H + base) = yo;
  float ss = y0 * y0 + y1 * y1;
#pragma unroll
  for (int d2 = 1; d2 < 64; d2 <<= 1) ss += __shfl_xor(ss, d2, 64);
  float nrm = fmaxf(sqrtf(ss), 1e-12f);
  float z0 = y0 / nrm, z1 = y1 / nrm;
  float lg[4];
#pragma unroll
  for (int rr = 0; rr < 4; ++rr)
    lg[rr] = z0 * cn[rr * 128 + lane * 2] + z1 * cn[rr * 128 + lane * 2 + 1];
#pragma unroll
  for (int d2 = 1; d2 < 64; d2 <<= 1) {
#pragma unroll
    for (int rr = 0; rr < 4; ++rr) lg[rr] += __shfl_xor(lg[rr], d2, 64);
  }
  float ts = 1.f / fmaxf(temp[0], 1e-4f);
#pragma unroll
  for (int rr = 0; rr < 4; ++rr) lg[rr] *= ts;
  float mx = fmaxf(fmaxf(lg[0], lg[1]), fmaxf(lg[2], lg[3]));
  float e0 = __expf(lg[0] - mx), e1 = __expf(lg[1] - mx);
  float e2 = __expf(lg[2] - mx), e3 = __expf(lg[3] - mx);
  float es = e0 + e1 + e2 + e3;
  float einv = 1.f / es;
  float p0 = e0 * einv, p1 = e1 * einv, p2 = e2 * einv, p3 = e3 * einv;
  if (lane < 4) {
    float pr = (lane == 0) ? p0 : (lane == 1) ? p1 : (lane == 2) ? p2 : p3;
    out[OUT_PROBS + (size_t)row * 4 + lane] = pr;
    float gi[3];
#pragma unroll
    for (int g = 0; g < 3; ++g) {
      const float* wr = wih + (g * 4 + lane) * 4;
      gi[g] = bih[g * 4 + lane] + wr[0] * p0 + wr[1] * p1 + wr[2] * p2 + wr[3] * p3;
    }
    const int b = row >> 10, t = row & 1023;
    float4 o4;
    o4.x = -LOG2E * (gi[0] + bhh[0 * 4 + lane]);
    o4.y = -LOG2E * (gi[1] + bhh[1 * 4 + lane]);
    o4.z = 2.f * LOG2E * gi[2];
    o4.w = pr;
    g4[(size_t)t * 64 + b * 4 + lane] = o4;
  }
}

// ---------------- speculative parallel GRU scan, 16 chunks of 64 ----------------
__global__ __launch_bounds__(512)
void k_scan(const float4* __restrict__ g4, const float* __restrict__ init,
            const float* __restrict__ whh, const float* __restrict__ bhh,
            float* __restrict__ out) {
  __shared__ float sbuf[4][2][32][64];
  const int tid = threadIdx.x;
  const int wave = tid >> 6, lane = tid & 63;
  const int blk = blockIdx.x;                 // 0..3

  if (wave < 4) {
    __builtin_amdgcn_s_setprio(1);
    const int ci = blk * 4 + wave;            // chunk 0..15
    const int t0 = ci * 64;
    const int start = (t0 >= 256) ? (t0 - 256) : 0;
    const int nwarm = (t0 - start) >> 5;
    const int r = lane & 3;
    const float sc[3] = {-LOG2E, -LOG2E, 2.f * LOG2E};
    float Wh[3][4];
#pragma unroll
    for (int g = 0; g < 3; ++g)
#pragma unroll
      for (int j = 0; j < 4; ++j) Wh[g][j] = whh[(g * 4 + r) * 4 + j] * sc[g];
    const float Bh2 = bhh[2 * 4 + r] * (2.f * LOG2E);
    float st = init[lane];

    const float4* gp = g4 + (size_t)start * 64 + lane;
    const float4* gpre = gp + 8 * 64;
    float4 pre[8];
#pragma unroll
    for (int d = 0; d < 8; ++d) pre[d] = gp[d * 64];

    auto do32 = [&](float* dstbuf) {
      for (int u = 0; u < 4; ++u) {
#pragma unroll
        for (int d = 0; d < 8; ++d) {
          float4 v = pre[d];
          pre[d] = gpre[d * 64];
          const float stm1 = st - 1.f;
          float s0 = qb0(st), s1 = qb1(st), s2 = qb2(st), s3 = qb3(st);
          float ar0 = fmaf(Wh[0][1], s1, fmaf(Wh[0][0], s0, v.x));
          float ar1 = fmaf(Wh[0][3], s3, Wh[0][2] * s2);
          float a_r = ar0 + ar1;
          float az0 = fmaf(Wh[1][1], s1, fmaf(Wh[1][0], s0, v.y));
          float az1 = fmaf(Wh[1][3], s3, Wh[1][2] * s2);
          float a_z = az0 + az1;
          float an0 = fmaf(Wh[2][1], s1, fmaf(Wh[2][0], s0, Bh2));
          float an1 = fmaf(Wh[2][3], s3, Wh[2][2] * s2);
          float g_n = an0 + an1;
          float rg = __builtin_amdgcn_rcpf(1.f + fexp2(a_r));
          float zg = __builtin_amdgcn_rcpf(1.f + fexp2(a_z));
          float zg09 = 0.9f * zg;
          float nxp = fmaf(rg, g_n, v.z);
          float rcpv = __builtin_amdgcn_rcpf(1.f + fexp2(nxp));
          float ng09 = fmaf(-1.8f, rcpv, 0.9f);
          float stmn = fmaf(2.f, rcpv, stm1);
          float base2 = fmaf(0.1f, v.w, ng09);
          float sn = fmaf(zg09, stmn, base2);
          st = sn;
          if (dstbuf) dstbuf[(u * 8 + d) * 64 + lane] = sn;
        }
        gpre += 8 * 64;
      }
    };

    for (int c = 0; c < nwarm; ++c) do32(nullptr);
    for (int s = 0; s < 3; ++s) {
      if (s < 2) do32(&sbuf[wave][s][0][0]);
      __syncthreads();
    }
    if (ci == 15) out[OUT_FS + lane] = st;
  } else {
    const int w2 = wave - 4;
    const int tbase = (blk * 4 + w2) * 64;
    for (int s = 0; s < 3; ++s) {
      if (s >= 1) {
        const float* src = &sbuf[w2][s - 1][0][0];
        const int tb = tbase + (s - 1) * 32;
#pragma unroll
        for (int k = 0; k < 8; ++k) {
          const int linear = k * 64 + lane;
          const int tl = linear & 31, b = linear >> 5;
          float4 v = *(const float4*)&src[tl * 64 + b * 4];
          const int t = tb + tl;
          *(float4*)&out[OUT_SP + (size_t)b * 4096 + t * 4] = v;
          int am = 0; float bv = v.x;
          if (v.y > bv) { bv = v.y; am = 1; }
          if (v.z > bv) { bv = v.z; am = 2; }
          if (v.w > bv) { bv = v.w; am = 3; }
          out[OUT_REG + (size_t)b * 1024 + t] = (float)am;
        }
      }
      __syncthreads();
    }
  }
}

// ---------------- launch ----------------
extern "C" void kernel_launch(void* const* d_in, const int* in_sizes, int n_in,
                              void* d_out, int out_size, void* d_ws, size_t ws_size,
                              hipStream_t stream) {
  (void)in_sizes; (void)n_in; (void)out_size; (void)ws_size;
  const float* x     = (const float*)d_in[0];
  const float* init  = (const float*)d_in[1];
  const float* in_w  = (const float*)d_in[2];
  const float* in_b  = (const float*)d_in[3];
  const float* qkv_w = (const float*)d_in[4];
  const float* qkv_b = (const float*)d_in[5];
  const float* out_w = (const float*)d_in[6];
  const float* out_b = (const float*)d_in[7];
  const float* ln1w  = (const float*)d_in[8];
  const float* ln1b  = (const float*)d_in[9];
  const float* ff1w  = (const float*)d_in[10];
  const float* ff1b  = (const float*)d_in[11];
  const float* ff2w  = (const float*)d_in[12];
  const float* ff2b  = (const float*)d_in[13];
  const float* ln2w  = (const float*)d_in[14];
  const float* ln2b  = (const float*)d_in[15];
  const float* nw    = (const float*)d_in[16];
  const float* nb    = (const float*)d_in[17];
  const float* cent  = (const float*)d_in[18];
  const float* temp  = (const float*)d_in[19];
  const float* gwih  = (const float*)d_in[20];
  const float* gwhh  = (const float*)d_in[21];
  const float* gbih  = (const float*)d_in[22];
  const float* gbhh  = (const float*)d_in[23];
  float* out = (float*)d_out;

  char* wsp = (char*)d_ws;
  auto take = [&](size_t bytes) -> char* {
    char* p = wsp;
    wsp += (bytes + 255) & ~(size_t)255;
    return p;
  };
  u16* xhi = (u16*)take((size_t)1048576 * 2);
  u16* xlo = (u16*)take((size_t)1048576 * 2);
  float* hf = (float*)take((size_t)M_ * 128 * 4);
  u16* hhi = (u16*)take((size_t)M_ * 128 * 2);
  u16* hlo = (u16*)take((size_t)M_ * 128 * 2);
  char* U = take(33554432);                 // union: qkv planes / ff1 planes
  u16* qkvhi = (u16*)U;
  u16* qkvlo = (u16*)(U + 12582912);
  u16* f1hi = (u16*)U;
  u16* f1lo = (u16*)(U + 16777216);
  u16* vthi = (u16*)take((size_t)2097152 * 2);
  u16* vtlo = (u16*)take((size_t)2097152 * 2);
  u16* ohi = (u16*)take((size_t)2097152 * 2);
  u16* olo = (u16*)take((size_t)2097152 * 2);
  u16* inwhi = (u16*)take(8192 * 2);   u16* inwlo = (u16*)take(8192 * 2);
  u16* qwhi = (u16*)take(196608 * 2);  u16* qwlo = (u16*)take(196608 * 2);
  u16* owhi = (u16*)take(65536 * 2);   u16* owlo = (u16*)take(65536 * 2);
  u16* f1whi = (u16*)take(262144 * 2); u16* f1wlo = (u16*)take(262144 * 2);
  u16* f2whi = (u16*)take(262144 * 2); u16* f2wlo = (u16*)take(262144 * 2);
  float* cnorm = (float*)take(512 * 4);
  float4* g4 = (float4*)take((size_t)(T_ + 8) * 64 * 16);

  k_split6<<<1801, 256, 0, stream>>>(x, xhi, xlo, in_w, inwhi, inwlo,
                                     qkv_w, qwhi, qwlo, out_w, owhi, owlo,
                                     ff1w, f1whi, f1wlo, ff2w, f2whi, f2wlo,
                                     cent, cnorm);

  k_gemm<0, 3, 0><<<dim3(128, 1), 256, 0, stream>>>(xhi, xlo, inwhi, inwlo, in_b,
                                                    hf, hhi, hlo, nullptr, nullptr, 128, 64);

  for (int l = 0; l < 4; ++l) {
    k_gemm<0, 2, 1><<<dim3(128, 3), 256, 0, stream>>>(
        hhi, hlo, qwhi + l * 49152, qwlo + l * 49152, qkv_b + l * 384,
        nullptr, qkvhi, qkvlo, vthi, vtlo, 384, 128);
    k_attn<<<512, 512, 0, stream>>>(qkvhi, qkvlo, vthi, vtlo, ohi, olo);
    k_gemm_ln<4><<<512, 256, 0, stream>>>(
        ohi, olo, owhi + l * 16384, owlo + l * 16384, out_b + l * 128,
        hf, ln1w + l * 128, ln1b + l * 128, hf, hhi, hlo);
    k_gemm<1, 2, 0><<<dim3(128, 4), 256, 0, stream>>>(
        hhi, hlo, f1whi + l * 65536, f1wlo + l * 65536, ff1b + l * 512,
        nullptr, f1hi, f1lo, nullptr, nullptr, 512, 128);
    k_gemm_ln<16><<<512, 256, 0, stream>>>(
        f1hi, f1lo, f2whi + l * 65536, f2wlo + l * 65536, ff2b + l * 128,
        hf, ln2w + l * 128, ln2b + l * 128, hf, hhi, hlo);
  }

  k_head<<<4096, 256, 0, stream>>>(hf, nw, nb, cnorm, temp, gwih, gbih, gbhh, g4, out);
  k_scan<<<4, 512, 0, stream>>>(g4, init, gwhh, gbhh, out);
}

// Round 18
// 399.864 us; speedup vs baseline: 1.0078x; 1.0078x over previous
//
#include <hip/hip_runtime.h>
#include <cstdint>
#include <cstddef>

#define B_    16
#define T_    1024
#define NF_   64
#define D_    128
#define H_    4
#define DFF_  512
#define M_    16384   // B_*T_

#define OUT_SP     0
#define OUT_REG    65536
#define OUT_PROBS  81920
#define OUT_H      147456
#define OUT_FS     2244608

#define LOG2E 1.4426950408889634f
#define SWZ(x) (((x) & 3) ^ (((x) >> 2) & 3))

typedef float f32x4 __attribute__((ext_vector_type(4)));
typedef short bf16x8 __attribute__((ext_vector_type(8)));
typedef unsigned short u16;
typedef unsigned int u32;

// native 2^x (v_exp_f32, 1ulp)
__device__ __forceinline__ float fexp2(float x) {
  float r;
  asm("v_exp_f32 %0, %1" : "=v"(r) : "v"(x));
  return r;
}
__device__ __forceinline__ float b2f(u16 b) {
  union { u32 u; float f; } x; x.u = ((u32)b) << 16; return x.f;
}
// HW bf16 conversions
__device__ __forceinline__ void bsplit(float v, u16& h, u16& l) {
  __bf16 hb = (__bf16)v;
  float rec = (float)hb;
  __bf16 lb = (__bf16)(v - rec);
  h = __builtin_bit_cast(u16, hb);
  l = __builtin_bit_cast(u16, lb);
}
__device__ __forceinline__ u16 bhi(float v) {
  __bf16 hb = (__bf16)v;
  return __builtin_bit_cast(u16, hb);
}
__device__ __forceinline__ void gload16(const void* g, void* l) {
  __builtin_amdgcn_global_load_lds((const __attribute__((address_space(1))) void*)g,
                                   (__attribute__((address_space(3))) void*)l, 16, 0, 0);
}
__device__ __forceinline__ f32x4 mfma_bf16(bf16x8 a, bf16x8 b, f32x4 c) {
  return __builtin_amdgcn_mfma_f32_16x16x32_bf16(a, b, c, 0, 0, 0);
}

// DPP helpers: pure-VALU cross-lane (no LDS pipe)
template <int CTRL>
__device__ __forceinline__ float fdpp(float x) {
  int i = __builtin_bit_cast(int, x);
  i = __builtin_amdgcn_mov_dpp(i, CTRL, 0xf, 0xf, true);
  return __builtin_bit_cast(float, i);
}
__device__ __forceinline__ float red16_sum(float x) {
  x += fdpp<0xB1>(x);
  x += fdpp<0x4E>(x);
  x += fdpp<0x124>(x);
  x += fdpp<0x128>(x);
  return x;
}
__device__ __forceinline__ float qb0(float x) { return fdpp<0x00>(x); }
__device__ __forceinline__ float qb1(float x) { return fdpp<0x55>(x); }
__device__ __forceinline__ float qb2(float x) { return fdpp<0xAA>(x); }
__device__ __forceinline__ float qb3(float x) { return fdpp<0xFF>(x); }

// ---------------- fused split (vec4) of 6 fp32 tensors + centroid normalization ----------------
__global__ __launch_bounds__(256)
void k_split6(const float* __restrict__ s0, u16* h0, u16* l0,
              const float* __restrict__ s1, u16* h1, u16* l1,
              const float* __restrict__ s2, u16* h2, u16* l2,
              const float* __restrict__ s3, u16* h3, u16* l3,
              const float* __restrict__ s4, u16* h4, u16* l4,
              const float* __restrict__ s5, u16* h5, u16* l5,
              const float* __restrict__ cent, float* __restrict__ cn) {
  if (blockIdx.x == 1800) {           // folded k_cnorm (one wave)
    const int lane = threadIdx.x;
    if (lane < 64) {
      for (int r = 0; r < 4; ++r) {
        float2 v = *(const float2*)&cent[r * 128 + lane * 2];
        float ss = v.x * v.x + v.y * v.y;
#pragma unroll
        for (int d = 1; d < 64; d <<= 1) ss += __shfl_xor(ss, d, 64);
        float nrm = fmaxf(sqrtf(ss), 1e-12f);
        float2 o; o.x = v.x / nrm; o.y = v.y / nrm;
        *(float2*)&cn[r * 128 + lane * 2] = o;
      }
    }
    return;
  }
  int i = blockIdx.x * 256 + threadIdx.x;   // vec4 index, 0..460799
  const float* s; u16 *h, *l; int j;
  if      (i < 262144) { s = s0; h = h0; l = l0; j = i; }
  else if (i < 264192) { s = s1; h = h1; l = l1; j = i - 262144; }
  else if (i < 313344) { s = s2; h = h2; l = l2; j = i - 264192; }
  else if (i < 329728) { s = s3; h = h3; l = l3; j = i - 313344; }
  else if (i < 395264) { s = s4; h = h4; l = l4; j = i - 329728; }
  else                 { s = s5; h = h5; l = l5; j = i - 395264; }
  float4 v = *(const float4*)&s[(size_t)j * 4];
  ushort4 hh, ll;
  bsplit(v.x, hh.x, ll.x);
  bsplit(v.y, hh.y, ll.y);
  bsplit(v.z, hh.z, ll.z);
  bsplit(v.w, hh.w, ll.w);
  *(ushort4*)&h[(size_t)j * 4] = hh;
  *(ushort4*)&l[(size_t)j * 4] = ll;
}

// ---------------- split-bf16 GEMM, 128x64 tile, double-buffered staging ----------------
template <int RELU, int OUTMODE, int VT>
__global__ __launch_bounds__(256)
void k_gemm(const u16* __restrict__ Ahi, const u16* __restrict__ Alo,
            const u16* __restrict__ Whi, const u16* __restrict__ Wlo,
            const float* __restrict__ bias,
            float* __restrict__ Cf, u16* __restrict__ Chi, u16* __restrict__ Clo,
            u16* __restrict__ vth, u16* __restrict__ vtl,
            int N, int K) {
  __shared__ u16 lA[2][2][128 * 32];
  __shared__ u16 lB[2][2][64 * 32];
  const int tid = threadIdx.x;
  const int wv = tid >> 6, lane = tid & 63;
  const int lo16 = lane & 15, hi2 = lane >> 4;
  const int m0 = blockIdx.x * 128, n0 = blockIdx.y * 64;
  const int ar = tid >> 2;
  const int slot = tid & 3;
  const int ac = ((slot ^ SWZ(ar)) * 8);
  const int dst = ar * 32 + slot * 8;
  const int aslot = ((hi2 ^ SWZ(lo16)) * 8);

  f32x4 acc[2][4];
#pragma unroll
  for (int i = 0; i < 2; ++i)
#pragma unroll
    for (int j = 0; j < 4; ++j) acc[i][j] = (f32x4){0.f, 0.f, 0.f, 0.f};

  auto stage = [&](int buf, int k0) {
    gload16(Ahi + (size_t)(m0 + ar) * K + k0 + ac,      &lA[buf][0][dst]);
    gload16(Ahi + (size_t)(m0 + 64 + ar) * K + k0 + ac, &lA[buf][0][64 * 32 + dst]);
    gload16(Alo + (size_t)(m0 + ar) * K + k0 + ac,      &lA[buf][1][dst]);
    gload16(Alo + (size_t)(m0 + 64 + ar) * K + k0 + ac, &lA[buf][1][64 * 32 + dst]);
    gload16(Whi + (size_t)(n0 + ar) * K + k0 + ac,      &lB[buf][0][dst]);
    gload16(Wlo + (size_t)(n0 + ar) * K + k0 + ac,      &lB[buf][1][dst]);
  };
  const int nks = K >> 5;
  stage(0, 0);
  for (int ks = 0; ks < nks; ++ks) {
    const int cur = ks & 1;
    if (ks + 1 < nks) {
      stage(cur ^ 1, (ks + 1) * 32);
      asm volatile("s_waitcnt vmcnt(6)" ::: "memory");
    } else {
      asm volatile("s_waitcnt vmcnt(0)" ::: "memory");
    }
    __builtin_amdgcn_s_barrier();

    bf16x8 af[2][2];
#pragma unroll
    for (int rt = 0; rt < 2; ++rt)
#pragma unroll
      for (int p = 0; p < 2; ++p)
        af[rt][p] = *(const bf16x8*)&lA[cur][p][(wv * 32 + rt * 16 + lo16) * 32 + aslot];
#pragma unroll
    for (int ct = 0; ct < 4; ++ct) {
      bf16x8 bf0 = *(const bf16x8*)&lB[cur][0][(ct * 16 + lo16) * 32 + aslot];
      bf16x8 bf1 = *(const bf16x8*)&lB[cur][1][(ct * 16 + lo16) * 32 + aslot];
#pragma unroll
      for (int rt = 0; rt < 2; ++rt) {
        acc[rt][ct] = mfma_bf16(af[rt][0], bf0, acc[rt][ct]);
        acc[rt][ct] = mfma_bf16(af[rt][0], bf1, acc[rt][ct]);
        acc[rt][ct] = mfma_bf16(af[rt][1], bf0, acc[rt][ct]);
      }
    }
    __builtin_amdgcn_s_barrier();
  }

  if (VT && n0 >= 256) {
#pragma unroll
    for (int rt = 0; rt < 2; ++rt)
#pragma unroll
      for (int ct = 0; ct < 4; ++ct) {
        const int col = n0 + ct * 16 + lo16;
        const float bc = bias[col];
        const int cv = col - 256;
        const int hh = cv >> 5, d = cv & 31;
        const int row0 = m0 + wv * 32 + rt * 16 + hi2 * 4;
        const int b = row0 >> 10, t0 = row0 & 1023;
        ushort4 sh, sl;
#pragma unroll
        for (int r = 0; r < 4; ++r) {
          float v = acc[rt][ct][r] + bc;
          u16 hbb, lbb;
          bsplit(v, hbb, lbb);
          ((u16*)&sh)[r] = hbb;
          ((u16*)&sl)[r] = lbb;
        }
        const size_t o = ((size_t)((b * 4 + hh) * 32 + d)) * 1024 + t0;
        *(ushort4*)&vth[o] = sh;
        *(ushort4*)&vtl[o] = sl;
      }
    return;
  }

#pragma unroll
  for (int rt = 0; rt < 2; ++rt)
#pragma unroll
    for (int ct = 0; ct < 4; ++ct) {
      const int col = n0 + ct * 16 + lo16;
      const float bc = bias[col];
#pragma unroll
      for (int r = 0; r < 4; ++r) {
        const int row = m0 + wv * 32 + rt * 16 + hi2 * 4 + r;
        float v = acc[rt][ct][r] + bc;
        if (RELU) v = fmaxf(v, 0.f);
        const size_t idx = (size_t)row * N + col;
        if (OUTMODE & 1) Cf[idx] = v;
        if (OUTMODE & 2) {
          u16 hb, lb;
          bsplit(v, hb, lb);
          Chi[idx] = hb;
          Clo[idx] = lb;
        }
      }
    }
}

// ---------------- fused GEMM (N=128) + residual + LayerNorm, BM=32, 2 blocks/CU ----------------
template <int KSTEPS>
__global__ __launch_bounds__(256)
void k_gemm_ln(const u16* __restrict__ Ahi, const u16* __restrict__ Alo,
               const u16* __restrict__ Whi, const u16* __restrict__ Wlo,
               const float* __restrict__ bias, const float* __restrict__ hres,
               const float* __restrict__ lnw, const float* __restrict__ lnb,
               float* __restrict__ hf, u16* __restrict__ hhi, u16* __restrict__ hlo) {
  __shared__ u16 lA[2][2][32 * 32];
  __shared__ u16 lB[2][2][128 * 32];
  __shared__ float part[2][32][2];
  const int tid = threadIdx.x;
  const int wv = tid >> 6, lane = tid & 63;
  const int lo16 = lane & 15, hi2 = lane >> 4;
  const int rg = wv & 1, ch = wv >> 1;
  const int m0 = blockIdx.x * 32;
  const int K = KSTEPS * 32;
  const int ap = tid >> 7;
  const int arow = (tid & 127) >> 2;
  const int aslt = tid & 3;
  const int aac = ((aslt ^ SWZ(arow)) * 8);
  const int br = tid >> 2;
  const int bac = ((aslt ^ SWZ(br)) * 8);
  const int bdst = br * 32 + aslt * 8;
  const int rslot = ((hi2 ^ SWZ(lo16)) * 8);

  f32x4 acc[4];
#pragma unroll
  for (int j = 0; j < 4; ++j) acc[j] = (f32x4){0.f, 0.f, 0.f, 0.f};

  auto stage = [&](int buf, int k0) {
    const u16* Asrc = ap ? Alo : Ahi;
    gload16(Asrc + (size_t)(m0 + arow) * K + k0 + aac, &lA[buf][ap][(tid & 127) * 8]);
    gload16(Whi + (size_t)br * K + k0 + bac,        &lB[buf][0][bdst]);
    gload16(Whi + (size_t)(64 + br) * K + k0 + bac, &lB[buf][0][64 * 32 + bdst]);
    gload16(Wlo + (size_t)br * K + k0 + bac,        &lB[buf][1][bdst]);
    gload16(Wlo + (size_t)(64 + br) * K + k0 + bac, &lB[buf][1][64 * 32 + bdst]);
  };
  stage(0, 0);
  for (int ks = 0; ks < KSTEPS; ++ks) {
    const int cur = ks & 1;
    if (ks + 1 < KSTEPS) {
      stage(cur ^ 1, (ks + 1) * 32);
      asm volatile("s_waitcnt vmcnt(5)" ::: "memory");
    } else {
      asm volatile("s_waitcnt vmcnt(0)" ::: "memory");
    }
    __builtin_amdgcn_s_barrier();

    bf16x8 af0 = *(const bf16x8*)&lA[cur][0][(rg * 16 + lo16) * 32 + rslot];
    bf16x8 af1 = *(const bf16x8*)&lA[cur][1][(rg * 16 + lo16) * 32 + rslot];
#pragma unroll
    for (int ct2 = 0; ct2 < 4; ++ct2) {
      const int ct = ch * 4 + ct2;
      bf16x8 bf0 = *(const bf16x8*)&lB[cur][0][(ct * 16 + lo16) * 32 + rslot];
      bf16x8 bf1 = *(const bf16x8*)&lB[cur][1][(ct * 16 + lo16) * 32 + rslot];
      acc[ct2] = mfma_bf16(af0, bf0, acc[ct2]);
      acc[ct2] = mfma_bf16(af0, bf1, acc[ct2]);
      acc[ct2] = mfma_bf16(af1, bf0, acc[ct2]);
    }
    __builtin_amdgcn_s_barrier();
  }

  float w4[4], b4[4], bi4[4];
#pragma unroll
  for (int ct2 = 0; ct2 < 4; ++ct2) {
    const int col = ch * 64 + ct2 * 16 + lo16;
    w4[ct2] = lnw[col]; b4[ct2] = lnb[col]; bi4[ct2] = bias[col];
  }
  float vals[4][4];
#pragma unroll
  for (int r = 0; r < 4; ++r) {
    const int row = m0 + rg * 16 + hi2 * 4 + r;
    float sm = 0.f, sq = 0.f;
#pragma unroll
    for (int ct2 = 0; ct2 < 4; ++ct2) {
      float v = acc[ct2][r] + bi4[ct2] +
                hres[(size_t)row * 128 + ch * 64 + ct2 * 16 + lo16];
      vals[r][ct2] = v; sm += v; sq += v * v;
    }
    sm = red16_sum(sm);
    sq = red16_sum(sq);
    if (lo16 == 0) {
      part[ch][rg * 16 + hi2 * 4 + r][0] = sm;
      part[ch][rg * 16 + hi2 * 4 + r][1] = sq;
    }
  }
  __syncthreads();
#pragma unroll
  for (int r = 0; r < 4; ++r) {
    const int row = m0 + rg * 16 + hi2 * 4 + r;
    const int r32 = rg * 16 + hi2 * 4 + r;
    const float smT = part[0][r32][0] + part[1][r32][0];
    const float sqT = part[0][r32][1] + part[1][r32][1];
    const float mn = smT * (1.f / 128.f);
    const float inv = rsqrtf(sqT * (1.f / 128.f) - mn * mn + 1e-5f);
#pragma unroll
    for (int ct2 = 0; ct2 < 4; ++ct2) {
      float y = (vals[r][ct2] - mn) * inv * w4[ct2] + b4[ct2];
      const size_t idx = (size_t)row * 128 + ch * 64 + ct2 * 16 + lo16;
      hf[idx] = y;
      u16 hb, lb;
      bsplit(y, hb, lb);
      hhi[idx] = hb;
      hlo[idx] = lb;
    }
  }
}

// ---------------- flash attention: 512 threads / 128 q-rows per block,
//                  K/V staged once for 8 waves, P stored as bf16-hi ONLY ----------------
__global__ __launch_bounds__(512)
void k_attn(const u16* __restrict__ qkh, const u16* __restrict__ qkl,
            const u16* __restrict__ vth, const u16* __restrict__ vtl,
            u16* __restrict__ ohi, u16* __restrict__ olo) {
  __shared__ u16 lK[2][2][64 * 32];
  __shared__ u16 lV[2][2][32 * 64];
  __shared__ u16 lP[8][16 * 72];

  const int tid = threadIdx.x;
  const int wv = tid >> 6, lane = tid & 63;
  const int lo16 = lane & 15, hi2 = lane >> 4;
  const int bid = blockIdx.x;          // 0..511
  const int xcd = bid & 7, g = bid >> 3;
  const int bh = xcd * 8 + (g & 7);
  const int qp = g >> 3;               // 0..7: 128-row q block
  const int b = bh >> 2, h = bh & 3;
  const int st256 = tid & 255;
  const int ar = st256 >> 2, slot = st256 & 3;
  const int kac = ((slot ^ SWZ(ar)) * 8);
  const int kdst = ar * 32 + slot * 8;
  const int vrow = st256 >> 3, vslot = st256 & 7;
  const int vac = ((vslot ^ (vrow & 7)) * 8);
  const bool isK = tid < 256;

  const int qrow = qp * 128 + wv * 16 + lo16;
  const size_t qoff = ((size_t)b * T_ + qrow) * 384 + h * 32 + hi2 * 8;
  bf16x8 qf0 = *(const bf16x8*)&qkh[qoff];
  bf16x8 qf1 = *(const bf16x8*)&qkl[qoff];

  bf16x8 onesf;
#pragma unroll
  for (int j = 0; j < 8; ++j) onesf[j] = (short)0x3F80;

  auto stage = [&](int buf, int kt) {
    if (isK) {
      const size_t krow0 = (size_t)b * T_ + kt * 64;
      gload16(qkh + (krow0 + ar) * 384 + 128 + h * 32 + kac, &lK[buf][0][kdst]);
      gload16(qkl + (krow0 + ar) * 384 + 128 + h * 32 + kac, &lK[buf][1][kdst]);
    } else {
      const size_t vsrc = ((size_t)bh * 32 + vrow) * T_ + kt * 64 + vac;
      gload16(vth + vsrc, &lV[buf][0][vrow * 64 + vslot * 8]);
      gload16(vtl + vsrc, &lV[buf][1][vrow * 64 + vslot * 8]);
    }
  };

  u16* lPp = &lP[wv][0];
  f32x4 oacc[2];
  oacc[0] = (f32x4){0.f, 0.f, 0.f, 0.f};
  oacc[1] = (f32x4){0.f, 0.f, 0.f, 0.f};
  f32x4 lracc = (f32x4){0.f, 0.f, 0.f, 0.f};
  const float cs = 0.17677669529663687f * LOG2E;
  const int kso = ((hi2 ^ SWZ(lo16)) * 8);

  stage(0, 0);
  asm volatile("s_waitcnt vmcnt(0)" ::: "memory");
  __builtin_amdgcn_s_barrier();

  for (int kt = 0; kt < 16; ++kt) {
    const int cur = kt & 1;
    if (kt < 15) stage(cur ^ 1, kt + 1);

    f32x4 s[4];
#pragma unroll
    for (int ct = 0; ct < 4; ++ct) {
      bf16x8 kf0 = *(const bf16x8*)&lK[cur][0][(ct * 16 + lo16) * 32 + kso];
      bf16x8 kf1 = *(const bf16x8*)&lK[cur][1][(ct * 16 + lo16) * 32 + kso];
      f32x4 z = (f32x4){0.f, 0.f, 0.f, 0.f};
      z = mfma_bf16(qf0, kf0, z);
      z = mfma_bf16(qf0, kf1, z);
      z = mfma_bf16(qf1, kf0, z);
      s[ct] = z;
    }
#pragma unroll
    for (int r = 0; r < 4; ++r) {
      float p0 = fexp2(s[0][r] * cs), p1 = fexp2(s[1][r] * cs);
      float p2 = fexp2(s[2][r] * cs), p3 = fexp2(s[3][r] * cs);
      const int prow = hi2 * 4 + r;
      lPp[prow * 72 + 0 * 16 + lo16] = bhi(p0);
      lPp[prow * 72 + 1 * 16 + lo16] = bhi(p1);
      lPp[prow * 72 + 2 * 16 + lo16] = bhi(p2);
      lPp[prow * 72 + 3 * 16 + lo16] = bhi(p3);
    }
    asm volatile("s_waitcnt lgkmcnt(0)" ::: "memory");
    __builtin_amdgcn_sched_barrier(0);
#pragma unroll
    for (int c = 0; c < 2; ++c) {
      bf16x8 ph = *(const bf16x8*)&lPp[lo16 * 72 + c * 32 + hi2 * 8];
      lracc = mfma_bf16(ph, onesf, lracc);
#pragma unroll
      for (int ct2 = 0; ct2 < 2; ++ct2) {
        const int d = ct2 * 16 + lo16;
        const int vso = (((c * 4 + hi2) ^ (lo16 & 7)) * 8);
        bf16x8 vf0 = *(const bf16x8*)&lV[cur][0][d * 64 + vso];
        bf16x8 vf1 = *(const bf16x8*)&lV[cur][1][d * 64 + vso];
        oacc[ct2] = mfma_bf16(ph, vf0, oacc[ct2]);
        oacc[ct2] = mfma_bf16(ph, vf1, oacc[ct2]);
      }
    }
    if (kt < 15) {
      asm volatile("s_waitcnt vmcnt(0)" ::: "memory");
      __builtin_amdgcn_s_barrier();
    }
  }
#pragma unroll
  for (int ct2 = 0; ct2 < 2; ++ct2)
#pragma unroll
    for (int r = 0; r < 4; ++r) {
      float v = oacc[ct2][r] * __builtin_amdgcn_rcpf(lracc[r]);
      const int t = qp * 128 + wv * 16 + hi2 * 4 + r;
      const size_t idx = ((size_t)b * T_ + t) * D_ + h * 32 + ct2 * 16 + lo16;
      u16 hb, lb;
      bsplit(v, hb, lb);
      ohi[idx] = hb;
      olo[idx] = lb;
    }
}

// ---------------- head: final LN -> h out, cosine logits -> probs + GRU gi precompute ----------------
__global__ __launch_bounds__(256)
void k_head(const float* __restrict__ hin, const float* __restrict__ w,
            const float* __restrict__ bws, const float* __restrict__ cn,
            const float* __restrict__ temp,
            const float* __restrict__ wih, const float* __restrict__ bih,
            const float* __restrict__ bhh,
            float4* __restrict__ g4, float* __restrict__ out) {
  const int row = blockIdx.x * 4 + (threadIdx.x >> 6);
  const int lane = threadIdx.x & 63;
  const size_t base = (size_t)row * D_ + lane * 2;
  float2 x = *(const float2*)(hin + base);
  float s = x.x + x.y;
#pragma unroll
  for (int d2 = 1; d2 < 64; d2 <<= 1) s += __shfl_xor(s, d2, 64);
  float m = s * (1.f / 128.f);
  float dx = x.x - m, dy = x.y - m;
  float q = dx * dx + dy * dy;
#pragma unroll
  for (int d2 = 1; d2 < 64; d2 <<= 1) q += __shfl_xor(q, d2, 64);
  float inv = rsqrtf(q * (1.f / 128.f) + 1e-5f);
  float2 ww = *(const float2*)(w + lane * 2);
  float2 bb = *(const float2*)(bws + lane * 2);
  float y0 = dx * inv * ww.x + bb.x;
  float y1 = dy * inv * ww.y + bb.y;
  float2 yo; yo.x = y0; yo.y = y1;
  *(float2*)(out + OUT_H + base) = yo;
  float ss = y0 * y0 + y1 * y1;
#pragma unroll
  for (int d2 = 1; d2 < 64; d2 <<= 1) ss += __shfl_xor(ss, d2, 64);
  float nrm = fmaxf(sqrtf(ss), 1e-12f);
  float z0 = y0 / nrm, z1 = y1 / nrm;
  float lg[4];
#pragma unroll
  for (int rr = 0; rr < 4; ++rr)
    lg[rr] = z0 * cn[rr * 128 + lane * 2] + z1 * cn[rr * 128 + lane * 2 + 1];
#pragma unroll
  for (int d2 = 1; d2 < 64; d2 <<= 1) {
#pragma unroll
    for (int rr = 0; rr < 4; ++rr) lg[rr] += __shfl_xor(lg[rr], d2, 64);
  }
  float ts = 1.f / fmaxf(temp[0], 1e-4f);
#pragma unroll
  for (int rr = 0; rr < 4; ++rr) lg[rr] *= ts;
  float mx = fmaxf(fmaxf(lg[0], lg[1]), fmaxf(lg[2], lg[3]));
  float e0 = __expf(lg[0] - mx), e1 = __expf(lg[1] - mx);
  float e2 = __expf(lg[2] - mx), e3 = __expf(lg[3] - mx);
  float es = e0 + e1 + e2 + e3;
  float einv = 1.f / es;
  float p0 = e0 * einv, p1 = e1 * einv, p2 = e2 * einv, p3 = e3 * einv;
  if (lane < 4) {
    float pr = (lane == 0) ? p0 : (lane == 1) ? p1 : (lane == 2) ? p2 : p3;
    out[OUT_PROBS + (size_t)row * 4 + lane] = pr;
    float gi[3];
#pragma unroll
    for (int g = 0; g < 3; ++g) {
      const float* wr = wih + (g * 4 + lane) * 4;
      gi[g] = bih[g * 4 + lane] + wr[0] * p0 + wr[1] * p1 + wr[2] * p2 + wr[3] * p3;
    }
    const int b = row >> 10, t = row & 1023;
    float4 o4;
    o4.x = -LOG2E * (gi[0] + bhh[0 * 4 + lane]);
    o4.y = -LOG2E * (gi[1] + bhh[1 * 4 + lane]);
    o4.z = 2.f * LOG2E * gi[2];
    o4.w = pr;
    g4[(size_t)t * 64 + b * 4 + lane] = o4;
  }
}

// ---------------- speculative parallel GRU scan, 16 chunks of 64 ----------------
__global__ __launch_bounds__(512)
void k_scan(const float4* __restrict__ g4, const float* __restrict__ init,
            const float* __restrict__ whh, const float* __restrict__ bhh,
            float* __restrict__ out) {
  __shared__ float sbuf[4][2][32][64];
  const int tid = threadIdx.x;
  const int wave = tid >> 6, lane = tid & 63;
  const int blk = blockIdx.x;                 // 0..3

  if (wave < 4) {
    __builtin_amdgcn_s_setprio(1);
    const int ci = blk * 4 + wave;            // chunk 0..15
    const int t0 = ci * 64;
    const int start = (t0 >= 256) ? (t0 - 256) : 0;
    const int nwarm = (t0 - start) >> 5;
    const int r = lane & 3;
    const float sc[3] = {-LOG2E, -LOG2E, 2.f * LOG2E};
    float Wh[3][4];
#pragma unroll
    for (int g = 0; g < 3; ++g)
#pragma unroll
      for (int j = 0; j < 4; ++j) Wh[g][j] = whh[(g * 4 + r) * 4 + j] * sc[g];
    const float Bh2 = bhh[2 * 4 + r] * (2.f * LOG2E);
    float st = init[lane];

    const float4* gp = g4 + (size_t)start * 64 + lane;
    const float4* gpre = gp + 8 * 64;
    float4 pre[8];
#pragma unroll
    for (int d = 0; d < 8; ++d) pre[d] = gp[d * 64];

    auto do32 = [&](float* dstbuf) {
      for (int u = 0; u < 4; ++u) {
#pragma unroll
        for (int d = 0; d < 8; ++d) {
          float4 v = pre[d];
          pre[d] = gpre[d * 64];
          const float stm1 = st - 1.f;
          float s0 = qb0(st), s1 = qb1(st), s2 = qb2(st), s3 = qb3(st);
          float ar0 = fmaf(Wh[0][1], s1, fmaf(Wh[0][0], s0, v.x));
          float ar1 = fmaf(Wh[0][3], s3, Wh[0][2] * s2);
          float a_r = ar0 + ar1;
          float az0 = fmaf(Wh[1][1], s1, fmaf(Wh[1][0], s0, v.y));
          float az1 = fmaf(Wh[1][3], s3, Wh[1][2] * s2);
          float a_z = az0 + az1;
          float an0 = fmaf(Wh[2][1], s1, fmaf(Wh[2][0], s0, Bh2));
          float an1 = fmaf(Wh[2][3], s3, Wh[2][2] * s2);
          float g_n = an0 + an1;
          float rg = __builtin_amdgcn_rcpf(1.f + fexp2(a_r));
          float zg = __builtin_amdgcn_rcpf(1.f + fexp2(a_z));
          float zg09 = 0.9f * zg;
          float nxp = fmaf(rg, g_n, v.z);
          float rcpv = __builtin_amdgcn_rcpf(1.f + fexp2(nxp));
          float ng09 = fmaf(-1.8f, rcpv, 0.9f);
          float stmn = fmaf(2.f, rcpv, stm1);
          float base2 = fmaf(0.1f, v.w, ng09);
          float sn = fmaf(zg09, stmn, base2);
          st = sn;
          if (dstbuf) dstbuf[(u * 8 + d) * 64 + lane] = sn;
        }
        gpre += 8 * 64;
      }
    };

    for (int c = 0; c < nwarm; ++c) do32(nullptr);
    for (int s = 0; s < 3; ++s) {
      if (s < 2) do32(&sbuf[wave][s][0][0]);
      __syncthreads();
    }
    if (ci == 15) out[OUT_FS + lane] = st;
  } else {
    const int w2 = wave - 4;
    const int tbase = (blk * 4 + w2) * 64;
    for (int s = 0; s < 3; ++s) {
      if (s >= 1) {
        const float* src = &sbuf[w2][s - 1][0][0];
        const int tb = tbase + (s - 1) * 32;
#pragma unroll
        for (int k = 0; k < 8; ++k) {
          const int linear = k * 64 + lane;
          const int tl = linear & 31, b = linear >> 5;
          float4 v = *(const float4*)&src[tl * 64 + b * 4];
          const int t = tb + tl;
          *(float4*)&out[OUT_SP + (size_t)b * 4096 + t * 4] = v;
          int am = 0; float bv = v.x;
          if (v.y > bv) { bv = v.y; am = 1; }
          if (v.z > bv) { bv = v.z; am = 2; }
          if (v.w > bv) { bv = v.w; am = 3; }
          out[OUT_REG + (size_t)b * 1024 + t] = (float)am;
        }
      }
      __syncthreads();
    }
  }
}

// ---------------- launch ----------------
extern "C" void kernel_launch(void* const* d_in, const int* in_sizes, int n_in,
                              void* d_out, int out_size, void* d_ws, size_t ws_size,
                              hipStream_t stream) {
  (void)in_sizes; (void)n_in; (void)out_size; (void)ws_size;
  const float* x     = (const float*)d_in[0];
  const float* init  = (const float*)d_in[1];
  const float* in_w  = (const float*)d_in[2];
  const float* in_b  = (const float*)d_in[3];
  const float* qkv_w = (const float*)d_in[4];
  const float* qkv_b = (const float*)d_in[5];
  const float* out_w = (const float*)d_in[6];
  const float* out_b = (const float*)d_in[7];
  const float* ln1w  = (const float*)d_in[8];
  const float* ln1b  = (const float*)d_in[9];
  const float* ff1w  = (const float*)d_in[10];
  const float* ff1b  = (const float*)d_in[11];
  const float* ff2w  = (const float*)d_in[12];
  const float* ff2b  = (const float*)d_in[13];
  const float* ln2w  = (const float*)d_in[14];
  const float* ln2b  = (const float*)d_in[15];
  const float* nw    = (const float*)d_in[16];
  const float* nb    = (const float*)d_in[17];
  const float* cent  = (const float*)d_in[18];
  const float* temp  = (const float*)d_in[19];
  const float* gwih  = (const float*)d_in[20];
  const float* gwhh  = (const float*)d_in[21];
  const float* gbih  = (const float*)d_in[22];
  const float* gbhh  = (const float*)d_in[23];
  float* out = (float*)d_out;

  char* wsp = (char*)d_ws;
  auto take = [&](size_t bytes) -> char* {
    char* p = wsp;
    wsp += (bytes + 255) & ~(size_t)255;
    return p;
  };
  u16* xhi = (u16*)take((size_t)1048576 * 2);
  u16* xlo = (u16*)take((size_t)1048576 * 2);
  float* hf = (float*)take((size_t)M_ * 128 * 4);
  u16* hhi = (u16*)take((size_t)M_ * 128 * 2);
  u16* hlo = (u16*)take((size_t)M_ * 128 * 2);
  char* U = take(33554432);                 // union: qkv planes / ff1 planes
  u16* qkvhi = (u16*)U;
  u16* qkvlo = (u16*)(U + 12582912);
  u16* f1hi = (u16*)U;
  u16* f1lo = (u16*)(U + 16777216);
  u16* vthi = (u16*)take((size_t)2097152 * 2);
  u16* vtlo = (u16*)take((size_t)2097152 * 2);
  u16* ohi = (u16*)take((size_t)2097152 * 2);
  u16* olo = (u16*)take((size_t)2097152 * 2);
  u16* inwhi = (u16*)take(8192 * 2);   u16* inwlo = (u16*)take(8192 * 2);
  u16* qwhi = (u16*)take(196608 * 2);  u16* qwlo = (u16*)take(196608 * 2);
  u16* owhi = (u16*)take(65536 * 2);   u16* owlo = (u16*)take(65536 * 2);
  u16* f1whi = (u16*)take(262144 * 2); u16* f1wlo = (u16*)take(262144 * 2);
  u16* f2whi = (u16*)take(262144 * 2); u16* f2wlo = (u16*)take(262144 * 2);
  float* cnorm = (float*)take(512 * 4);
  float4* g4 = (float4*)take((size_t)(T_ + 8) * 64 * 16);

  k_split6<<<1801, 256, 0, stream>>>(x, xhi, xlo, in_w, inwhi, inwlo,
                                     qkv_w, qwhi, qwlo, out_w, owhi, owlo,
                                     ff1w, f1whi, f1wlo, ff2w, f2whi, f2wlo,
                                     cent, cnorm);

  k_gemm<0, 3, 0><<<dim3(128, 2), 256, 0, stream>>>(xhi, xlo, inwhi, inwlo, in_b,
                                                    hf, hhi, hlo, nullptr, nullptr, 128, 64);

  for (int l = 0; l < 4; ++l) {
    k_gemm<0, 2, 1><<<dim3(128, 6), 256, 0, stream>>>(
        hhi, hlo, qwhi + l * 49152, qwlo + l * 49152, qkv_b + l * 384,
        nullptr, qkvhi, qkvlo, vthi, vtlo, 384, 128);
    k_attn<<<512, 512, 0, stream>>>(qkvhi, qkvlo, vthi, vtlo, ohi, olo);
    k_gemm_ln<4><<<512, 256, 0, stream>>>(
        ohi, olo, owhi + l * 16384, owlo + l * 16384, out_b + l * 128,
        hf, ln1w + l * 128, ln1b + l * 128, hf, hhi, hlo);
    k_gemm<1, 2, 0><<<dim3(128, 8), 256, 0, stream>>>(
        hhi, hlo, f1whi + l * 65536, f1wlo + l * 65536, ff1b + l * 512,
        nullptr, f1hi, f1lo, nullptr, nullptr, 512, 128);
    k_gemm_ln<16><<<512, 256, 0, stream>>>(
        f1hi, f1lo, f2whi + l * 65536, f2wlo + l * 65536, ff2b + l * 128,
        hf, ln2w + l * 128, ln2b + l * 128, hf, hhi, hlo);
  }

  k_head<<<4096, 256, 0, stream>>>(hf, nw, nb, cnorm, temp, gwih, gbih, gbhh, g4, out);
  k_scan<<<4, 512, 0, stream>>>(g4, init, gwhh, gbhh, out);
}

// Round 19
// 381.904 us; speedup vs baseline: 1.0552x; 1.0470x over previous
//
#include <hip/hip_runtime.h>
#include <cstdint>
#include <cstddef>

#define B_    16
#define T_    1024
#define NF_   64
#define D_    128
#define H_    4
#define DFF_  512
#define M_    16384   // B_*T_

#define OUT_SP     0
#define OUT_REG    65536
#define OUT_PROBS  81920
#define OUT_H      147456
#define OUT_FS     2244608

#define LOG2E 1.4426950408889634f
#define SWZ(x) (((x) & 3) ^ (((x) >> 2) & 3))

typedef float f32x4 __attribute__((ext_vector_type(4)));
typedef short bf16x8 __attribute__((ext_vector_type(8)));
typedef unsigned short u16;
typedef unsigned int u32;

// native 2^x (v_exp_f32, 1ulp)
__device__ __forceinline__ float fexp2(float x) {
  float r;
  asm("v_exp_f32 %0, %1" : "=v"(r) : "v"(x));
  return r;
}
__device__ __forceinline__ float b2f(u16 b) {
  union { u32 u; float f; } x; x.u = ((u32)b) << 16; return x.f;
}
// HW bf16 conversions
__device__ __forceinline__ void bsplit(float v, u16& h, u16& l) {
  __bf16 hb = (__bf16)v;
  float rec = (float)hb;
  __bf16 lb = (__bf16)(v - rec);
  h = __builtin_bit_cast(u16, hb);
  l = __builtin_bit_cast(u16, lb);
}
__device__ __forceinline__ u16 bhi(float v) {
  __bf16 hb = (__bf16)v;
  return __builtin_bit_cast(u16, hb);
}
__device__ __forceinline__ void gload16(const void* g, void* l) {
  __builtin_amdgcn_global_load_lds((const __attribute__((address_space(1))) void*)g,
                                   (__attribute__((address_space(3))) void*)l, 16, 0, 0);
}
__device__ __forceinline__ f32x4 mfma_bf16(bf16x8 a, bf16x8 b, f32x4 c) {
  return __builtin_amdgcn_mfma_f32_16x16x32_bf16(a, b, c, 0, 0, 0);
}

// DPP helpers: pure-VALU cross-lane (no LDS pipe)
template <int CTRL>
__device__ __forceinline__ float fdpp(float x) {
  int i = __builtin_bit_cast(int, x);
  i = __builtin_amdgcn_mov_dpp(i, CTRL, 0xf, 0xf, true);
  return __builtin_bit_cast(float, i);
}
__device__ __forceinline__ float red16_sum(float x) {
  x += fdpp<0xB1>(x);
  x += fdpp<0x4E>(x);
  x += fdpp<0x124>(x);
  x += fdpp<0x128>(x);
  return x;
}
__device__ __forceinline__ float qb0(float x) { return fdpp<0x00>(x); }
__device__ __forceinline__ float qb1(float x) { return fdpp<0x55>(x); }
__device__ __forceinline__ float qb2(float x) { return fdpp<0xAA>(x); }
__device__ __forceinline__ float qb3(float x) { return fdpp<0xFF>(x); }

// ---------------- fused split (vec4) of 6 fp32 tensors + centroid normalization ----------------
__global__ __launch_bounds__(256)
void k_split6(const float* __restrict__ s0, u16* h0, u16* l0,
              const float* __restrict__ s1, u16* h1, u16* l1,
              const float* __restrict__ s2, u16* h2, u16* l2,
              const float* __restrict__ s3, u16* h3, u16* l3,
              const float* __restrict__ s4, u16* h4, u16* l4,
              const float* __restrict__ s5, u16* h5, u16* l5,
              const float* __restrict__ cent, float* __restrict__ cn) {
  if (blockIdx.x == 1800) {           // folded k_cnorm (one wave)
    const int lane = threadIdx.x;
    if (lane < 64) {
      for (int r = 0; r < 4; ++r) {
        float2 v = *(const float2*)&cent[r * 128 + lane * 2];
        float ss = v.x * v.x + v.y * v.y;
#pragma unroll
        for (int d = 1; d < 64; d <<= 1) ss += __shfl_xor(ss, d, 64);
        float nrm = fmaxf(sqrtf(ss), 1e-12f);
        float2 o; o.x = v.x / nrm; o.y = v.y / nrm;
        *(float2*)&cn[r * 128 + lane * 2] = o;
      }
    }
    return;
  }
  int i = blockIdx.x * 256 + threadIdx.x;   // vec4 index, 0..460799
  const float* s; u16 *h, *l; int j;
  if      (i < 262144) { s = s0; h = h0; l = l0; j = i; }
  else if (i < 264192) { s = s1; h = h1; l = l1; j = i - 262144; }
  else if (i < 313344) { s = s2; h = h2; l = l2; j = i - 264192; }
  else if (i < 329728) { s = s3; h = h3; l = l3; j = i - 313344; }
  else if (i < 395264) { s = s4; h = h4; l = l4; j = i - 329728; }
  else                 { s = s5; h = h5; l = l5; j = i - 395264; }
  float4 v = *(const float4*)&s[(size_t)j * 4];
  ushort4 hh, ll;
  bsplit(v.x, hh.x, ll.x);
  bsplit(v.y, hh.y, ll.y);
  bsplit(v.z, hh.z, ll.z);
  bsplit(v.w, hh.w, ll.w);
  *(ushort4*)&h[(size_t)j * 4] = hh;
  *(ushort4*)&l[(size_t)j * 4] = ll;
}

// ---------------- split-bf16 GEMM, 128x64 tile, double-buffered staging ----------------
template <int RELU, int OUTMODE, int VT>
__global__ __launch_bounds__(256)
void k_gemm(const u16* __restrict__ Ahi, const u16* __restrict__ Alo,
            const u16* __restrict__ Whi, const u16* __restrict__ Wlo,
            const float* __restrict__ bias,
            float* __restrict__ Cf, u16* __restrict__ Chi, u16* __restrict__ Clo,
            u16* __restrict__ vth, u16* __restrict__ vtl,
            int N, int K) {
  __shared__ u16 lA[2][2][128 * 32];
  __shared__ u16 lB[2][2][64 * 32];
  const int tid = threadIdx.x;
  const int wv = tid >> 6, lane = tid & 63;
  const int lo16 = lane & 15, hi2 = lane >> 4;
  const int m0 = blockIdx.x * 128, n0 = blockIdx.y * 64;
  const int ar = tid >> 2;
  const int slot = tid & 3;
  const int ac = ((slot ^ SWZ(ar)) * 8);
  const int dst = ar * 32 + slot * 8;
  const int aslot = ((hi2 ^ SWZ(lo16)) * 8);

  f32x4 acc[2][4];
#pragma unroll
  for (int i = 0; i < 2; ++i)
#pragma unroll
    for (int j = 0; j < 4; ++j) acc[i][j] = (f32x4){0.f, 0.f, 0.f, 0.f};

  auto stage = [&](int buf, int k0) {
    gload16(Ahi + (size_t)(m0 + ar) * K + k0 + ac,      &lA[buf][0][dst]);
    gload16(Ahi + (size_t)(m0 + 64 + ar) * K + k0 + ac, &lA[buf][0][64 * 32 + dst]);
    gload16(Alo + (size_t)(m0 + ar) * K + k0 + ac,      &lA[buf][1][dst]);
    gload16(Alo + (size_t)(m0 + 64 + ar) * K + k0 + ac, &lA[buf][1][64 * 32 + dst]);
    gload16(Whi + (size_t)(n0 + ar) * K + k0 + ac,      &lB[buf][0][dst]);
    gload16(Wlo + (size_t)(n0 + ar) * K + k0 + ac,      &lB[buf][1][dst]);
  };
  const int nks = K >> 5;
  stage(0, 0);
  for (int ks = 0; ks < nks; ++ks) {
    const int cur = ks & 1;
    if (ks + 1 < nks) {
      stage(cur ^ 1, (ks + 1) * 32);
      asm volatile("s_waitcnt vmcnt(6)" ::: "memory");
    } else {
      asm volatile("s_waitcnt vmcnt(0)" ::: "memory");
    }
    __builtin_amdgcn_s_barrier();

    bf16x8 af[2][2];
#pragma unroll
    for (int rt = 0; rt < 2; ++rt)
#pragma unroll
      for (int p = 0; p < 2; ++p)
        af[rt][p] = *(const bf16x8*)&lA[cur][p][(wv * 32 + rt * 16 + lo16) * 32 + aslot];
#pragma unroll
    for (int ct = 0; ct < 4; ++ct) {
      bf16x8 bf0 = *(const bf16x8*)&lB[cur][0][(ct * 16 + lo16) * 32 + aslot];
      bf16x8 bf1 = *(const bf16x8*)&lB[cur][1][(ct * 16 + lo16) * 32 + aslot];
#pragma unroll
      for (int rt = 0; rt < 2; ++rt) {
        acc[rt][ct] = mfma_bf16(af[rt][0], bf0, acc[rt][ct]);
        acc[rt][ct] = mfma_bf16(af[rt][0], bf1, acc[rt][ct]);
        acc[rt][ct] = mfma_bf16(af[rt][1], bf0, acc[rt][ct]);
      }
    }
    __builtin_amdgcn_s_barrier();
  }

  if (VT && n0 >= 256) {
#pragma unroll
    for (int rt = 0; rt < 2; ++rt)
#pragma unroll
      for (int ct = 0; ct < 4; ++ct) {
        const int col = n0 + ct * 16 + lo16;
        const float bc = bias[col];
        const int cv = col - 256;
        const int hh = cv >> 5, d = cv & 31;
        const int row0 = m0 + wv * 32 + rt * 16 + hi2 * 4;
        const int b = row0 >> 10, t0 = row0 & 1023;
        ushort4 sh, sl;
#pragma unroll
        for (int r = 0; r < 4; ++r) {
          float v = acc[rt][ct][r] + bc;
          u16 hbb, lbb;
          bsplit(v, hbb, lbb);
          ((u16*)&sh)[r] = hbb;
          ((u16*)&sl)[r] = lbb;
        }
        const size_t o = ((size_t)((b * 4 + hh) * 32 + d)) * 1024 + t0;
        *(ushort4*)&vth[o] = sh;
        *(ushort4*)&vtl[o] = sl;
      }
    return;
  }

#pragma unroll
  for (int rt = 0; rt < 2; ++rt)
#pragma unroll
    for (int ct = 0; ct < 4; ++ct) {
      const int col = n0 + ct * 16 + lo16;
      const float bc = bias[col];
#pragma unroll
      for (int r = 0; r < 4; ++r) {
        const int row = m0 + wv * 32 + rt * 16 + hi2 * 4 + r;
        float v = acc[rt][ct][r] + bc;
        if (RELU) v = fmaxf(v, 0.f);
        const size_t idx = (size_t)row * N + col;
        if (OUTMODE & 1) Cf[idx] = v;
        if (OUTMODE & 2) {
          u16 hb, lb;
          bsplit(v, hb, lb);
          Chi[idx] = hb;
          Clo[idx] = lb;
        }
      }
    }
}

// ---------------- fused GEMM (N=128) + residual + LayerNorm, BM=32, 2 blocks/CU ----------------
// APREC: 2 = A hi+lo planes; 1 = A hi-only (skips the af1 MFMA; lo buffer unused)
template <int KSTEPS, int APREC>
__global__ __launch_bounds__(256)
void k_gemm_ln(const u16* __restrict__ Ahi, const u16* __restrict__ Alo,
               const u16* __restrict__ Whi, const u16* __restrict__ Wlo,
               const float* __restrict__ bias, const float* __restrict__ hres,
               const float* __restrict__ lnw, const float* __restrict__ lnb,
               float* __restrict__ hf, u16* __restrict__ hhi, u16* __restrict__ hlo) {
  __shared__ u16 lA[2][2][32 * 32];
  __shared__ u16 lB[2][2][128 * 32];
  __shared__ float part[2][32][2];
  const int tid = threadIdx.x;
  const int wv = tid >> 6, lane = tid & 63;
  const int lo16 = lane & 15, hi2 = lane >> 4;
  const int rg = wv & 1, ch = wv >> 1;
  const int m0 = blockIdx.x * 32;
  const int K = KSTEPS * 32;
  const int ap = tid >> 7;
  const int arow = (tid & 127) >> 2;
  const int aslt = tid & 3;
  const int aac = ((aslt ^ SWZ(arow)) * 8);
  const int br = tid >> 2;
  const int bac = ((aslt ^ SWZ(br)) * 8);
  const int bdst = br * 32 + aslt * 8;
  const int rslot = ((hi2 ^ SWZ(lo16)) * 8);

  f32x4 acc[4];
#pragma unroll
  for (int j = 0; j < 4; ++j) acc[j] = (f32x4){0.f, 0.f, 0.f, 0.f};

  auto stage = [&](int buf, int k0) {
    // APREC==1: ap=1 threads re-load hi (uniform load count; lo plane unused)
    const u16* Asrc = (APREC == 2 && ap) ? Alo : Ahi;
    gload16(Asrc + (size_t)(m0 + arow) * K + k0 + aac, &lA[buf][ap][(tid & 127) * 8]);
    gload16(Whi + (size_t)br * K + k0 + bac,        &lB[buf][0][bdst]);
    gload16(Whi + (size_t)(64 + br) * K + k0 + bac, &lB[buf][0][64 * 32 + bdst]);
    gload16(Wlo + (size_t)br * K + k0 + bac,        &lB[buf][1][bdst]);
    gload16(Wlo + (size_t)(64 + br) * K + k0 + bac, &lB[buf][1][64 * 32 + bdst]);
  };
  stage(0, 0);
  for (int ks = 0; ks < KSTEPS; ++ks) {
    const int cur = ks & 1;
    if (ks + 1 < KSTEPS) {
      stage(cur ^ 1, (ks + 1) * 32);
      asm volatile("s_waitcnt vmcnt(5)" ::: "memory");
    } else {
      asm volatile("s_waitcnt vmcnt(0)" ::: "memory");
    }
    __builtin_amdgcn_s_barrier();

    bf16x8 af0 = *(const bf16x8*)&lA[cur][0][(rg * 16 + lo16) * 32 + rslot];
    bf16x8 af1;
    if (APREC == 2) af1 = *(const bf16x8*)&lA[cur][1][(rg * 16 + lo16) * 32 + rslot];
#pragma unroll
    for (int ct2 = 0; ct2 < 4; ++ct2) {
      const int ct = ch * 4 + ct2;
      bf16x8 bf0 = *(const bf16x8*)&lB[cur][0][(ct * 16 + lo16) * 32 + rslot];
      bf16x8 bf1 = *(const bf16x8*)&lB[cur][1][(ct * 16 + lo16) * 32 + rslot];
      acc[ct2] = mfma_bf16(af0, bf0, acc[ct2]);
      acc[ct2] = mfma_bf16(af0, bf1, acc[ct2]);
      if (APREC == 2) acc[ct2] = mfma_bf16(af1, bf0, acc[ct2]);
    }
    __builtin_amdgcn_s_barrier();
  }

  float w4[4], b4[4], bi4[4];
#pragma unroll
  for (int ct2 = 0; ct2 < 4; ++ct2) {
    const int col = ch * 64 + ct2 * 16 + lo16;
    w4[ct2] = lnw[col]; b4[ct2] = lnb[col]; bi4[ct2] = bias[col];
  }
  float vals[4][4];
#pragma unroll
  for (int r = 0; r < 4; ++r) {
    const int row = m0 + rg * 16 + hi2 * 4 + r;
    float sm = 0.f, sq = 0.f;
#pragma unroll
    for (int ct2 = 0; ct2 < 4; ++ct2) {
      float v = acc[ct2][r] + bi4[ct2] +
                hres[(size_t)row * 128 + ch * 64 + ct2 * 16 + lo16];
      vals[r][ct2] = v; sm += v; sq += v * v;
    }
    sm = red16_sum(sm);
    sq = red16_sum(sq);
    if (lo16 == 0) {
      part[ch][rg * 16 + hi2 * 4 + r][0] = sm;
      part[ch][rg * 16 + hi2 * 4 + r][1] = sq;
    }
  }
  __syncthreads();
#pragma unroll
  for (int r = 0; r < 4; ++r) {
    const int row = m0 + rg * 16 + hi2 * 4 + r;
    const int r32 = rg * 16 + hi2 * 4 + r;
    const float smT = part[0][r32][0] + part[1][r32][0];
    const float sqT = part[0][r32][1] + part[1][r32][1];
    const float mn = smT * (1.f / 128.f);
    const float inv = rsqrtf(sqT * (1.f / 128.f) - mn * mn + 1e-5f);
#pragma unroll
    for (int ct2 = 0; ct2 < 4; ++ct2) {
      float y = (vals[r][ct2] - mn) * inv * w4[ct2] + b4[ct2];
      const size_t idx = (size_t)row * 128 + ch * 64 + ct2 * 16 + lo16;
      hf[idx] = y;
      u16 hb, lb;
      bsplit(y, hb, lb);
      hhi[idx] = hb;
      hlo[idx] = lb;
    }
  }
}

// ---------------- flash attention: 512 threads / 128 q-rows per block,
//                  K/V staged once for 8 waves, P bf16-hi only, o hi-only out ----------------
__global__ __launch_bounds__(512)
void k_attn(const u16* __restrict__ qkh, const u16* __restrict__ qkl,
            const u16* __restrict__ vth, const u16* __restrict__ vtl,
            u16* __restrict__ ohi) {
  __shared__ u16 lK[2][2][64 * 32];
  __shared__ u16 lV[2][2][32 * 64];
  __shared__ u16 lP[8][16 * 72];

  const int tid = threadIdx.x;
  const int wv = tid >> 6, lane = tid & 63;
  const int lo16 = lane & 15, hi2 = lane >> 4;
  const int bid = blockIdx.x;          // 0..511
  const int xcd = bid & 7, g = bid >> 3;
  const int bh = xcd * 8 + (g & 7);
  const int qp = g >> 3;               // 0..7: 128-row q block
  const int b = bh >> 2, h = bh & 3;
  const int st256 = tid & 255;
  const int ar = st256 >> 2, slot = st256 & 3;
  const int kac = ((slot ^ SWZ(ar)) * 8);
  const int kdst = ar * 32 + slot * 8;
  const int vrow = st256 >> 3, vslot = st256 & 7;
  const int vac = ((vslot ^ (vrow & 7)) * 8);
  const bool isK = tid < 256;

  const int qrow = qp * 128 + wv * 16 + lo16;
  const size_t qoff = ((size_t)b * T_ + qrow) * 384 + h * 32 + hi2 * 8;
  bf16x8 qf0 = *(const bf16x8*)&qkh[qoff];
  bf16x8 qf1 = *(const bf16x8*)&qkl[qoff];

  bf16x8 onesf;
#pragma unroll
  for (int j = 0; j < 8; ++j) onesf[j] = (short)0x3F80;

  auto stage = [&](int buf, int kt) {
    if (isK) {
      const size_t krow0 = (size_t)b * T_ + kt * 64;
      gload16(qkh + (krow0 + ar) * 384 + 128 + h * 32 + kac, &lK[buf][0][kdst]);
      gload16(qkl + (krow0 + ar) * 384 + 128 + h * 32 + kac, &lK[buf][1][kdst]);
    } else {
      const size_t vsrc = ((size_t)bh * 32 + vrow) * T_ + kt * 64 + vac;
      gload16(vth + vsrc, &lV[buf][0][vrow * 64 + vslot * 8]);
      gload16(vtl + vsrc, &lV[buf][1][vrow * 64 + vslot * 8]);
    }
  };

  u16* lPp = &lP[wv][0];
  f32x4 oacc[2];
  oacc[0] = (f32x4){0.f, 0.f, 0.f, 0.f};
  oacc[1] = (f32x4){0.f, 0.f, 0.f, 0.f};
  f32x4 lracc = (f32x4){0.f, 0.f, 0.f, 0.f};
  const float cs = 0.17677669529663687f * LOG2E;
  const int kso = ((hi2 ^ SWZ(lo16)) * 8);

  stage(0, 0);
  asm volatile("s_waitcnt vmcnt(0)" ::: "memory");
  __builtin_amdgcn_s_barrier();

  for (int kt = 0; kt < 16; ++kt) {
    const int cur = kt & 1;
    if (kt < 15) stage(cur ^ 1, kt + 1);

    f32x4 s[4];
#pragma unroll
    for (int ct = 0; ct < 4; ++ct) {
      bf16x8 kf0 = *(const bf16x8*)&lK[cur][0][(ct * 16 + lo16) * 32 + kso];
      bf16x8 kf1 = *(const bf16x8*)&lK[cur][1][(ct * 16 + lo16) * 32 + kso];
      f32x4 z = (f32x4){0.f, 0.f, 0.f, 0.f};
      z = mfma_bf16(qf0, kf0, z);
      z = mfma_bf16(qf0, kf1, z);
      z = mfma_bf16(qf1, kf0, z);
      s[ct] = z;
    }
#pragma unroll
    for (int r = 0; r < 4; ++r) {
      float p0 = fexp2(s[0][r] * cs), p1 = fexp2(s[1][r] * cs);
      float p2 = fexp2(s[2][r] * cs), p3 = fexp2(s[3][r] * cs);
      const int prow = hi2 * 4 + r;
      lPp[prow * 72 + 0 * 16 + lo16] = bhi(p0);
      lPp[prow * 72 + 1 * 16 + lo16] = bhi(p1);
      lPp[prow * 72 + 2 * 16 + lo16] = bhi(p2);
      lPp[prow * 72 + 3 * 16 + lo16] = bhi(p3);
    }
    asm volatile("s_waitcnt lgkmcnt(0)" ::: "memory");
    __builtin_amdgcn_sched_barrier(0);
#pragma unroll
    for (int c = 0; c < 2; ++c) {
      bf16x8 ph = *(const bf16x8*)&lPp[lo16 * 72 + c * 32 + hi2 * 8];
      lracc = mfma_bf16(ph, onesf, lracc);
#pragma unroll
      for (int ct2 = 0; ct2 < 2; ++ct2) {
        const int d = ct2 * 16 + lo16;
        const int vso = (((c * 4 + hi2) ^ (lo16 & 7)) * 8);
        bf16x8 vf0 = *(const bf16x8*)&lV[cur][0][d * 64 + vso];
        bf16x8 vf1 = *(const bf16x8*)&lV[cur][1][d * 64 + vso];
        oacc[ct2] = mfma_bf16(ph, vf0, oacc[ct2]);
        oacc[ct2] = mfma_bf16(ph, vf1, oacc[ct2]);
      }
    }
    if (kt < 15) {
      asm volatile("s_waitcnt vmcnt(0)" ::: "memory");
      __builtin_amdgcn_s_barrier();
    }
  }
#pragma unroll
  for (int ct2 = 0; ct2 < 2; ++ct2)
#pragma unroll
    for (int r = 0; r < 4; ++r) {
      float v = oacc[ct2][r] * __builtin_amdgcn_rcpf(lracc[r]);
      const int t = qp * 128 + wv * 16 + hi2 * 4 + r;
      const size_t idx = ((size_t)b * T_ + t) * D_ + h * 32 + ct2 * 16 + lo16;
      ohi[idx] = bhi(v);            // hi-only: out-proj A is single-plane
    }
}

// ---------------- head: final LN -> h out, cosine logits -> probs + GRU gi precompute ----------------
__global__ __launch_bounds__(256)
void k_head(const float* __restrict__ hin, const float* __restrict__ w,
            const float* __restrict__ bws, const float* __restrict__ cn,
            const float* __restrict__ temp,
            const float* __restrict__ wih, const float* __restrict__ bih,
            const float* __restrict__ bhh,
            float4* __restrict__ g4, float* __restrict__ out) {
  const int row = blockIdx.x * 4 + (threadIdx.x >> 6);
  const int lane = threadIdx.x & 63;
  const size_t base = (size_t)row * D_ + lane * 2;
  float2 x = *(const float2*)(hin + base);
  float s = x.x + x.y;
#pragma unroll
  for (int d2 = 1; d2 < 64; d2 <<= 1) s += __shfl_xor(s, d2, 64);
  float m = s * (1.f / 128.f);
  float dx = x.x - m, dy = x.y - m;
  float q = dx * dx + dy * dy;
#pragma unroll
  for (int d2 = 1; d2 < 64; d2 <<= 1) q += __shfl_xor(q, d2, 64);
  float inv = rsqrtf(q * (1.f / 128.f) + 1e-5f);
  float2 ww = *(const float2*)(w + lane * 2);
  float2 bb = *(const float2*)(bws + lane * 2);
  float y0 = dx * inv * ww.x + bb.x;
  float y1 = dy * inv * ww.y + bb.y;
  float2 yo; yo.x = y0; yo.y = y1;
  *(float2*)(out + OUT_H + base) = yo;
  float ss = y0 * y0 + y1 * y1;
#pragma unroll
  for (int d2 = 1; d2 < 64; d2 <<= 1) ss += __shfl_xor(ss, d2, 64);
  float nrm = fmaxf(sqrtf(ss), 1e-12f);
  float z0 = y0 / nrm, z1 = y1 / nrm;
  float lg[4];
#pragma unroll
  for (int rr = 0; rr < 4; ++rr)
    lg[rr] = z0 * cn[rr * 128 + lane * 2] + z1 * cn[rr * 128 + lane * 2 + 1];
#pragma unroll
  for (int d2 = 1; d2 < 64; d2 <<= 1) {
#pragma unroll
    for (int rr = 0; rr < 4; ++rr) lg[rr] += __shfl_xor(lg[rr], d2, 64);
  }
  float ts = 1.f / fmaxf(temp[0], 1e-4f);
#pragma unroll
  for (int rr = 0; rr < 4; ++rr) lg[rr] *= ts;
  float mx = fmaxf(fmaxf(lg[0], lg[1]), fmaxf(lg[2], lg[3]));
  float e0 = __expf(lg[0] - mx), e1 = __expf(lg[1] - mx);
  float e2 = __expf(lg[2] - mx), e3 = __expf(lg[3] - mx);
  float es = e0 + e1 + e2 + e3;
  float einv = 1.f / es;
  float p0 = e0 * einv, p1 = e1 * einv, p2 = e2 * einv, p3 = e3 * einv;
  if (lane < 4) {
    float pr = (lane == 0) ? p0 : (lane == 1) ? p1 : (lane == 2) ? p2 : p3;
    out[OUT_PROBS + (size_t)row * 4 + lane] = pr;
    float gi[3];
#pragma unroll
    for (int g = 0; g < 3; ++g) {
      const float* wr = wih + (g * 4 + lane) * 4;
      gi[g] = bih[g * 4 + lane] + wr[0] * p0 + wr[1] * p1 + wr[2] * p2 + wr[3] * p3;
    }
    const int b = row >> 10, t = row & 1023;
    float4 o4;
    o4.x = -LOG2E * (gi[0] + bhh[0 * 4 + lane]);
    o4.y = -LOG2E * (gi[1] + bhh[1 * 4 + lane]);
    o4.z = 2.f * LOG2E * gi[2];
    o4.w = pr;
    g4[(size_t)t * 64 + b * 4 + lane] = o4;
  }
}

// ---------------- speculative parallel GRU scan, 16 chunks of 64, 128-step warmup ----------------
// warmup error <= ~0.9^128 * |init spread| ~ 1e-6 << existing 1e-2 bf16 floor
__global__ __launch_bounds__(512)
void k_scan(const float4* __restrict__ g4, const float* __restrict__ init,
            const float* __restrict__ whh, const float* __restrict__ bhh,
            float* __restrict__ out) {
  __shared__ float sbuf[4][2][32][64];
  const int tid = threadIdx.x;
  const int wave = tid >> 6, lane = tid & 63;
  const int blk = blockIdx.x;                 // 0..3

  if (wave < 4) {
    __builtin_amdgcn_s_setprio(1);
    const int ci = blk * 4 + wave;            // chunk 0..15
    const int t0 = ci * 64;
    const int start = (t0 >= 128) ? (t0 - 128) : 0;
    const int nwarm = (t0 - start) >> 5;
    const int r = lane & 3;
    const float sc[3] = {-LOG2E, -LOG2E, 2.f * LOG2E};
    float Wh[3][4];
#pragma unroll
    for (int g = 0; g < 3; ++g)
#pragma unroll
      for (int j = 0; j < 4; ++j) Wh[g][j] = whh[(g * 4 + r) * 4 + j] * sc[g];
    const float Bh2 = bhh[2 * 4 + r] * (2.f * LOG2E);
    float st = init[lane];

    const float4* gp = g4 + (size_t)start * 64 + lane;
    const float4* gpre = gp + 8 * 64;
    float4 pre[8];
#pragma unroll
    for (int d = 0; d < 8; ++d) pre[d] = gp[d * 64];

    auto do32 = [&](float* dstbuf) {
      for (int u = 0; u < 4; ++u) {
#pragma unroll
        for (int d = 0; d < 8; ++d) {
          float4 v = pre[d];
          pre[d] = gpre[d * 64];
          const float stm1 = st - 1.f;
          float s0 = qb0(st), s1 = qb1(st), s2 = qb2(st), s3 = qb3(st);
          float ar0 = fmaf(Wh[0][1], s1, fmaf(Wh[0][0], s0, v.x));
          float ar1 = fmaf(Wh[0][3], s3, Wh[0][2] * s2);
          float a_r = ar0 + ar1;
          float az0 = fmaf(Wh[1][1], s1, fmaf(Wh[1][0], s0, v.y));
          float az1 = fmaf(Wh[1][3], s3, Wh[1][2] * s2);
          float a_z = az0 + az1;
          float an0 = fmaf(Wh[2][1], s1, fmaf(Wh[2][0], s0, Bh2));
          float an1 = fmaf(Wh[2][3], s3, Wh[2][2] * s2);
          float g_n = an0 + an1;
          float rg = __builtin_amdgcn_rcpf(1.f + fexp2(a_r));
          float zg = __builtin_amdgcn_rcpf(1.f + fexp2(a_z));
          float zg09 = 0.9f * zg;
          float nxp = fmaf(rg, g_n, v.z);
          float rcpv = __builtin_amdgcn_rcpf(1.f + fexp2(nxp));
          float ng09 = fmaf(-1.8f, rcpv, 0.9f);
          float stmn = fmaf(2.f, rcpv, stm1);
          float base2 = fmaf(0.1f, v.w, ng09);
          float sn = fmaf(zg09, stmn, base2);
          st = sn;
          if (dstbuf) dstbuf[(u * 8 + d) * 64 + lane] = sn;
        }
        gpre += 8 * 64;
      }
    };

    for (int c = 0; c < nwarm; ++c) do32(nullptr);
    for (int s = 0; s < 3; ++s) {
      if (s < 2) do32(&sbuf[wave][s][0][0]);
      __syncthreads();
    }
    if (ci == 15) out[OUT_FS + lane] = st;
  } else {
    const int w2 = wave - 4;
    const int tbase = (blk * 4 + w2) * 64;
    for (int s = 0; s < 3; ++s) {
      if (s >= 1) {
        const float* src = &sbuf[w2][s - 1][0][0];
        const int tb = tbase + (s - 1) * 32;
#pragma unroll
        for (int k = 0; k < 8; ++k) {
          const int linear = k * 64 + lane;
          const int tl = linear & 31, b = linear >> 5;
          float4 v = *(const float4*)&src[tl * 64 + b * 4];
          const int t = tb + tl;
          *(float4*)&out[OUT_SP + (size_t)b * 4096 + t * 4] = v;
          int am = 0; float bv = v.x;
          if (v.y > bv) { bv = v.y; am = 1; }
          if (v.z > bv) { bv = v.z; am = 2; }
          if (v.w > bv) { bv = v.w; am = 3; }
          out[OUT_REG + (size_t)b * 1024 + t] = (float)am;
        }
      }
      __syncthreads();
    }
  }
}

// ---------------- launch ----------------
extern "C" void kernel_launch(void* const* d_in, const int* in_sizes, int n_in,
                              void* d_out, int out_size, void* d_ws, size_t ws_size,
                              hipStream_t stream) {
  (void)in_sizes; (void)n_in; (void)out_size; (void)ws_size;
  const float* x     = (const float*)d_in[0];
  const float* init  = (const float*)d_in[1];
  const float* in_w  = (const float*)d_in[2];
  const float* in_b  = (const float*)d_in[3];
  const float* qkv_w = (const float*)d_in[4];
  const float* qkv_b = (const float*)d_in[5];
  const float* out_w = (const float*)d_in[6];
  const float* out_b = (const float*)d_in[7];
  const float* ln1w  = (const float*)d_in[8];
  const float* ln1b  = (const float*)d_in[9];
  const float* ff1w  = (const float*)d_in[10];
  const float* ff1b  = (const float*)d_in[11];
  const float* ff2w  = (const float*)d_in[12];
  const float* ff2b  = (const float*)d_in[13];
  const float* ln2w  = (const float*)d_in[14];
  const float* ln2b  = (const float*)d_in[15];
  const float* nw    = (const float*)d_in[16];
  const float* nb    = (const float*)d_in[17];
  const float* cent  = (const float*)d_in[18];
  const float* temp  = (const float*)d_in[19];
  const float* gwih  = (const float*)d_in[20];
  const float* gwhh  = (const float*)d_in[21];
  const float* gbih  = (const float*)d_in[22];
  const float* gbhh  = (const float*)d_in[23];
  float* out = (float*)d_out;

  char* wsp = (char*)d_ws;
  auto take = [&](size_t bytes) -> char* {
    char* p = wsp;
    wsp += (bytes + 255) & ~(size_t)255;
    return p;
  };
  u16* xhi = (u16*)take((size_t)1048576 * 2);
  u16* xlo = (u16*)take((size_t)1048576 * 2);
  float* hf = (float*)take((size_t)M_ * 128 * 4);
  u16* hhi = (u16*)take((size_t)M_ * 128 * 2);
  u16* hlo = (u16*)take((size_t)M_ * 128 * 2);
  char* U = take(33554432);                 // union: qkv planes / ff1 planes
  u16* qkvhi = (u16*)U;
  u16* qkvlo = (u16*)(U + 12582912);
  u16* f1hi = (u16*)U;
  u16* f1lo = (u16*)(U + 16777216);
  u16* vthi = (u16*)take((size_t)2097152 * 2);
  u16* vtlo = (u16*)take((size_t)2097152 * 2);
  u16* ohi = (u16*)take((size_t)2097152 * 2);
  u16* olo = (u16*)take((size_t)2097152 * 2);   // unused (o hi-only); kept for layout
  u16* inwhi = (u16*)take(8192 * 2);   u16* inwlo = (u16*)take(8192 * 2);
  u16* qwhi = (u16*)take(196608 * 2);  u16* qwlo = (u16*)take(196608 * 2);
  u16* owhi = (u16*)take(65536 * 2);   u16* owlo = (u16*)take(65536 * 2);
  u16* f1whi = (u16*)take(262144 * 2); u16* f1wlo = (u16*)take(262144 * 2);
  u16* f2whi = (u16*)take(262144 * 2); u16* f2wlo = (u16*)take(262144 * 2);
  float* cnorm = (float*)take(512 * 4);
  float4* g4 = (float4*)take((size_t)(T_ + 8) * 64 * 16);

  k_split6<<<1801, 256, 0, stream>>>(x, xhi, xlo, in_w, inwhi, inwlo,
                                     qkv_w, qwhi, qwlo, out_w, owhi, owlo,
                                     ff1w, f1whi, f1wlo, ff2w, f2whi, f2wlo,
                                     cent, cnorm);

  k_gemm<0, 3, 0><<<dim3(128, 2), 256, 0, stream>>>(xhi, xlo, inwhi, inwlo, in_b,
                                                    hf, hhi, hlo, nullptr, nullptr, 128, 64);

  for (int l = 0; l < 4; ++l) {
    k_gemm<0, 2, 1><<<dim3(128, 6), 256, 0, stream>>>(
        hhi, hlo, qwhi + l * 49152, qwlo + l * 49152, qkv_b + l * 384,
        nullptr, qkvhi, qkvlo, vthi, vtlo, 384, 128);
    k_attn<<<512, 512, 0, stream>>>(qkvhi, qkvlo, vthi, vtlo, ohi);
    k_gemm_ln<4, 1><<<512, 256, 0, stream>>>(
        ohi, olo, owhi + l * 16384, owlo + l * 16384, out_b + l * 128,
        hf, ln1w + l * 128, ln1b + l * 128, hf, hhi, hlo);
    k_gemm<1, 2, 0><<<dim3(128, 8), 256, 0, stream>>>(
        hhi, hlo, f1whi + l * 65536, f1wlo + l * 65536, ff1b + l * 512,
        nullptr, f1hi, f1lo, nullptr, nullptr, 512, 128);
    k_gemm_ln<16, 2><<<512, 256, 0, stream>>>(
        f1hi, f1lo, f2whi + l * 65536, f2wlo + l * 65536, ff2b + l * 128,
        hf, ln2w + l * 128, ln2b + l * 128, hf, hhi, hlo);
  }

  k_head<<<4096, 256, 0, stream>>>(hf, nw, nb, cnorm, temp, gwih, gbih, gbhh, g4, out);
  k_scan<<<4, 512, 0, stream>>>(g4, init, gwhh, gbhh, out);
}

// Round 21
// 381.792 us; speedup vs baseline: 1.0555x; 1.0003x over previous
//
#include <hip/hip_runtime.h>
#include <cstdint>
#include <cstddef>

#define B_    16
#define T_    1024
#define NF_   64
#define D_    128
#define H_    4
#define DFF_  512
#define M_    16384   // B_*T_

#define OUT_SP     0
#define OUT_REG    65536
#define OUT_PROBS  81920
#define OUT_H      147456
#define OUT_FS     2244608

#define LOG2E 1.4426950408889634f
#define SWZ(x) (((x) & 3) ^ (((x) >> 2) & 3))

typedef float f32x4 __attribute__((ext_vector_type(4)));
typedef short bf16x8 __attribute__((ext_vector_type(8)));
typedef unsigned short u16;
typedef unsigned int u32;

// native 2^x (v_exp_f32, 1ulp)
__device__ __forceinline__ float fexp2(float x) {
  float r;
  asm("v_exp_f32 %0, %1" : "=v"(r) : "v"(x));
  return r;
}
__device__ __forceinline__ float b2f(u16 b) {
  union { u32 u; float f; } x; x.u = ((u32)b) << 16; return x.f;
}
// HW bf16 conversions
__device__ __forceinline__ void bsplit(float v, u16& h, u16& l) {
  __bf16 hb = (__bf16)v;
  float rec = (float)hb;
  __bf16 lb = (__bf16)(v - rec);
  h = __builtin_bit_cast(u16, hb);
  l = __builtin_bit_cast(u16, lb);
}
__device__ __forceinline__ u16 bhi(float v) {
  __bf16 hb = (__bf16)v;
  return __builtin_bit_cast(u16, hb);
}
__device__ __forceinline__ void gload16(const void* g, void* l) {
  __builtin_amdgcn_global_load_lds((const __attribute__((address_space(1))) void*)g,
                                   (__attribute__((address_space(3))) void*)l, 16, 0, 0);
}
__device__ __forceinline__ f32x4 mfma_bf16(bf16x8 a, bf16x8 b, f32x4 c) {
  return __builtin_amdgcn_mfma_f32_16x16x32_bf16(a, b, c, 0, 0, 0);
}

// DPP helpers: pure-VALU cross-lane (no LDS pipe)
template <int CTRL>
__device__ __forceinline__ float fdpp(float x) {
  int i = __builtin_bit_cast(int, x);
  i = __builtin_amdgcn_mov_dpp(i, CTRL, 0xf, 0xf, true);
  return __builtin_bit_cast(float, i);
}
__device__ __forceinline__ float red16_sum(float x) {
  x += fdpp<0xB1>(x);
  x += fdpp<0x4E>(x);
  x += fdpp<0x124>(x);
  x += fdpp<0x128>(x);
  return x;
}
__device__ __forceinline__ float qb0(float x) { return fdpp<0x00>(x); }
__device__ __forceinline__ float qb1(float x) { return fdpp<0x55>(x); }
__device__ __forceinline__ float qb2(float x) { return fdpp<0xAA>(x); }
__device__ __forceinline__ float qb3(float x) { return fdpp<0xFF>(x); }

// ---------------- fused split (vec4) of 6 fp32 tensors + centroid normalization ----------------
__global__ __launch_bounds__(256)
void k_split6(const float* __restrict__ s0, u16* h0, u16* l0,
              const float* __restrict__ s1, u16* h1, u16* l1,
              const float* __restrict__ s2, u16* h2, u16* l2,
              const float* __restrict__ s3, u16* h3, u16* l3,
              const float* __restrict__ s4, u16* h4, u16* l4,
              const float* __restrict__ s5, u16* h5, u16* l5,
              const float* __restrict__ cent, float* __restrict__ cn) {
  if (blockIdx.x == 1800) {           // folded k_cnorm (one wave)
    const int lane = threadIdx.x;
    if (lane < 64) {
      for (int r = 0; r < 4; ++r) {
        float2 v = *(const float2*)&cent[r * 128 + lane * 2];
        float ss = v.x * v.x + v.y * v.y;
#pragma unroll
        for (int d = 1; d < 64; d <<= 1) ss += __shfl_xor(ss, d, 64);
        float nrm = fmaxf(sqrtf(ss), 1e-12f);
        float2 o; o.x = v.x / nrm; o.y = v.y / nrm;
        *(float2*)&cn[r * 128 + lane * 2] = o;
      }
    }
    return;
  }
  int i = blockIdx.x * 256 + threadIdx.x;   // vec4 index, 0..460799
  const float* s; u16 *h, *l; int j;
  if      (i < 262144) { s = s0; h = h0; l = l0; j = i; }
  else if (i < 264192) { s = s1; h = h1; l = l1; j = i - 262144; }
  else if (i < 313344) { s = s2; h = h2; l = l2; j = i - 264192; }
  else if (i < 329728) { s = s3; h = h3; l = l3; j = i - 313344; }
  else if (i < 395264) { s = s4; h = h4; l = l4; j = i - 329728; }
  else                 { s = s5; h = h5; l = l5; j = i - 395264; }
  float4 v = *(const float4*)&s[(size_t)j * 4];
  ushort4 hh, ll;
  bsplit(v.x, hh.x, ll.x);
  bsplit(v.y, hh.y, ll.y);
  bsplit(v.z, hh.z, ll.z);
  bsplit(v.w, hh.w, ll.w);
  *(ushort4*)&h[(size_t)j * 4] = hh;
  *(ushort4*)&l[(size_t)j * 4] = ll;
}

// ---------------- split-bf16 GEMM, 128x64 tile, double-buffered staging ----------------
template <int RELU, int OUTMODE, int VT>
__global__ __launch_bounds__(256)
void k_gemm(const u16* __restrict__ Ahi, const u16* __restrict__ Alo,
            const u16* __restrict__ Whi, const u16* __restrict__ Wlo,
            const float* __restrict__ bias,
            float* __restrict__ Cf, u16* __restrict__ Chi, u16* __restrict__ Clo,
            u16* __restrict__ vth, u16* __restrict__ vtl,
            int N, int K) {
  __shared__ u16 lA[2][2][128 * 32];
  __shared__ u16 lB[2][2][64 * 32];
  const int tid = threadIdx.x;
  const int wv = tid >> 6, lane = tid & 63;
  const int lo16 = lane & 15, hi2 = lane >> 4;
  const int m0 = blockIdx.x * 128, n0 = blockIdx.y * 64;
  const int ar = tid >> 2;
  const int slot = tid & 3;
  const int ac = ((slot ^ SWZ(ar)) * 8);
  const int dst = ar * 32 + slot * 8;
  const int aslot = ((hi2 ^ SWZ(lo16)) * 8);

  f32x4 acc[2][4];
#pragma unroll
  for (int i = 0; i < 2; ++i)
#pragma unroll
    for (int j = 0; j < 4; ++j) acc[i][j] = (f32x4){0.f, 0.f, 0.f, 0.f};

  auto stage = [&](int buf, int k0) {
    gload16(Ahi + (size_t)(m0 + ar) * K + k0 + ac,      &lA[buf][0][dst]);
    gload16(Ahi + (size_t)(m0 + 64 + ar) * K + k0 + ac, &lA[buf][0][64 * 32 + dst]);
    gload16(Alo + (size_t)(m0 + ar) * K + k0 + ac,      &lA[buf][1][dst]);
    gload16(Alo + (size_t)(m0 + 64 + ar) * K + k0 + ac, &lA[buf][1][64 * 32 + dst]);
    gload16(Whi + (size_t)(n0 + ar) * K + k0 + ac,      &lB[buf][0][dst]);
    gload16(Wlo + (size_t)(n0 + ar) * K + k0 + ac,      &lB[buf][1][dst]);
  };
  const int nks = K >> 5;
  stage(0, 0);
  for (int ks = 0; ks < nks; ++ks) {
    const int cur = ks & 1;
    if (ks + 1 < nks) {
      stage(cur ^ 1, (ks + 1) * 32);
      asm volatile("s_waitcnt vmcnt(6)" ::: "memory");
    } else {
      asm volatile("s_waitcnt vmcnt(0)" ::: "memory");
    }
    __builtin_amdgcn_s_barrier();

    bf16x8 af[2][2];
#pragma unroll
    for (int rt = 0; rt < 2; ++rt)
#pragma unroll
      for (int p = 0; p < 2; ++p)
        af[rt][p] = *(const bf16x8*)&lA[cur][p][(wv * 32 + rt * 16 + lo16) * 32 + aslot];
#pragma unroll
    for (int ct = 0; ct < 4; ++ct) {
      bf16x8 bf0 = *(const bf16x8*)&lB[cur][0][(ct * 16 + lo16) * 32 + aslot];
      bf16x8 bf1 = *(const bf16x8*)&lB[cur][1][(ct * 16 + lo16) * 32 + aslot];
#pragma unroll
      for (int rt = 0; rt < 2; ++rt) {
        acc[rt][ct] = mfma_bf16(af[rt][0], bf0, acc[rt][ct]);
        acc[rt][ct] = mfma_bf16(af[rt][0], bf1, acc[rt][ct]);
        acc[rt][ct] = mfma_bf16(af[rt][1], bf0, acc[rt][ct]);
      }
    }
    __builtin_amdgcn_s_barrier();
  }

  if (VT && n0 >= 256) {
#pragma unroll
    for (int rt = 0; rt < 2; ++rt)
#pragma unroll
      for (int ct = 0; ct < 4; ++ct) {
        const int col = n0 + ct * 16 + lo16;
        const float bc = bias[col];
        const int cv = col - 256;
        const int hh = cv >> 5, d = cv & 31;
        const int row0 = m0 + wv * 32 + rt * 16 + hi2 * 4;
        const int b = row0 >> 10, t0 = row0 & 1023;
        ushort4 sh, sl;
#pragma unroll
        for (int r = 0; r < 4; ++r) {
          float v = acc[rt][ct][r] + bc;
          u16 hbb, lbb;
          bsplit(v, hbb, lbb);
          ((u16*)&sh)[r] = hbb;
          ((u16*)&sl)[r] = lbb;
        }
        const size_t o = ((size_t)((b * 4 + hh) * 32 + d)) * 1024 + t0;
        *(ushort4*)&vth[o] = sh;
        *(ushort4*)&vtl[o] = sl;
      }
    return;
  }

#pragma unroll
  for (int rt = 0; rt < 2; ++rt)
#pragma unroll
    for (int ct = 0; ct < 4; ++ct) {
      const int col = n0 + ct * 16 + lo16;
      const float bc = bias[col];
#pragma unroll
      for (int r = 0; r < 4; ++r) {
        const int row = m0 + wv * 32 + rt * 16 + hi2 * 4 + r;
        float v = acc[rt][ct][r] + bc;
        if (RELU) v = fmaxf(v, 0.f);
        const size_t idx = (size_t)row * N + col;
        if (OUTMODE & 1) Cf[idx] = v;
        if (OUTMODE & 2) {
          u16 hb, lb;
          bsplit(v, hb, lb);
          Chi[idx] = hb;
          Clo[idx] = lb;
        }
      }
    }
}

// ---------------- fused GEMM (N=128) + residual + LayerNorm, BM=32, 2 blocks/CU ----------------
// APREC: 2 = A hi+lo planes; 1 = A hi-only (skips the af1 MFMA; lo buffer unused)
template <int KSTEPS, int APREC>
__global__ __launch_bounds__(256)
void k_gemm_ln(const u16* __restrict__ Ahi, const u16* __restrict__ Alo,
               const u16* __restrict__ Whi, const u16* __restrict__ Wlo,
               const float* __restrict__ bias, const float* __restrict__ hres,
               const float* __restrict__ lnw, const float* __restrict__ lnb,
               float* __restrict__ hf, u16* __restrict__ hhi, u16* __restrict__ hlo) {
  __shared__ u16 lA[2][2][32 * 32];
  __shared__ u16 lB[2][2][128 * 32];
  __shared__ float part[2][32][2];
  const int tid = threadIdx.x;
  const int wv = tid >> 6, lane = tid & 63;
  const int lo16 = lane & 15, hi2 = lane >> 4;
  const int rg = wv & 1, ch = wv >> 1;
  const int m0 = blockIdx.x * 32;
  const int K = KSTEPS * 32;
  const int ap = tid >> 7;
  const int arow = (tid & 127) >> 2;
  const int aslt = tid & 3;
  const int aac = ((aslt ^ SWZ(arow)) * 8);
  const int br = tid >> 2;
  const int bac = ((aslt ^ SWZ(br)) * 8);
  const int bdst = br * 32 + aslt * 8;
  const int rslot = ((hi2 ^ SWZ(lo16)) * 8);

  f32x4 acc[4];
#pragma unroll
  for (int j = 0; j < 4; ++j) acc[j] = (f32x4){0.f, 0.f, 0.f, 0.f};

  auto stage = [&](int buf, int k0) {
    // APREC==1: ap=1 threads re-load hi (uniform load count; lo plane unused)
    const u16* Asrc = (APREC == 2 && ap) ? Alo : Ahi;
    gload16(Asrc + (size_t)(m0 + arow) * K + k0 + aac, &lA[buf][ap][(tid & 127) * 8]);
    gload16(Whi + (size_t)br * K + k0 + bac,        &lB[buf][0][bdst]);
    gload16(Whi + (size_t)(64 + br) * K + k0 + bac, &lB[buf][0][64 * 32 + bdst]);
    gload16(Wlo + (size_t)br * K + k0 + bac,        &lB[buf][1][bdst]);
    gload16(Wlo + (size_t)(64 + br) * K + k0 + bac, &lB[buf][1][64 * 32 + bdst]);
  };
  stage(0, 0);
  for (int ks = 0; ks < KSTEPS; ++ks) {
    const int cur = ks & 1;
    if (ks + 1 < KSTEPS) {
      stage(cur ^ 1, (ks + 1) * 32);
      asm volatile("s_waitcnt vmcnt(5)" ::: "memory");
    } else {
      asm volatile("s_waitcnt vmcnt(0)" ::: "memory");
    }
    __builtin_amdgcn_s_barrier();

    bf16x8 af0 = *(const bf16x8*)&lA[cur][0][(rg * 16 + lo16) * 32 + rslot];
    bf16x8 af1;
    if (APREC == 2) af1 = *(const bf16x8*)&lA[cur][1][(rg * 16 + lo16) * 32 + rslot];
#pragma unroll
    for (int ct2 = 0; ct2 < 4; ++ct2) {
      const int ct = ch * 4 + ct2;
      bf16x8 bf0 = *(const bf16x8*)&lB[cur][0][(ct * 16 + lo16) * 32 + rslot];
      bf16x8 bf1 = *(const bf16x8*)&lB[cur][1][(ct * 16 + lo16) * 32 + rslot];
      acc[ct2] = mfma_bf16(af0, bf0, acc[ct2]);
      acc[ct2] = mfma_bf16(af0, bf1, acc[ct2]);
      if (APREC == 2) acc[ct2] = mfma_bf16(af1, bf0, acc[ct2]);
    }
    __builtin_amdgcn_s_barrier();
  }

  float w4[4], b4[4], bi4[4];
#pragma unroll
  for (int ct2 = 0; ct2 < 4; ++ct2) {
    const int col = ch * 64 + ct2 * 16 + lo16;
    w4[ct2] = lnw[col]; b4[ct2] = lnb[col]; bi4[ct2] = bias[col];
  }
  float vals[4][4];
#pragma unroll
  for (int r = 0; r < 4; ++r) {
    const int row = m0 + rg * 16 + hi2 * 4 + r;
    float sm = 0.f, sq = 0.f;
#pragma unroll
    for (int ct2 = 0; ct2 < 4; ++ct2) {
      float v = acc[ct2][r] + bi4[ct2] +
                hres[(size_t)row * 128 + ch * 64 + ct2 * 16 + lo16];
      vals[r][ct2] = v; sm += v; sq += v * v;
    }
    sm = red16_sum(sm);
    sq = red16_sum(sq);
    if (lo16 == 0) {
      part[ch][rg * 16 + hi2 * 4 + r][0] = sm;
      part[ch][rg * 16 + hi2 * 4 + r][1] = sq;
    }
  }
  __syncthreads();
#pragma unroll
  for (int r = 0; r < 4; ++r) {
    const int row = m0 + rg * 16 + hi2 * 4 + r;
    const int r32 = rg * 16 + hi2 * 4 + r;
    const float smT = part[0][r32][0] + part[1][r32][0];
    const float sqT = part[0][r32][1] + part[1][r32][1];
    const float mn = smT * (1.f / 128.f);
    const float inv = rsqrtf(sqT * (1.f / 128.f) - mn * mn + 1e-5f);
#pragma unroll
    for (int ct2 = 0; ct2 < 4; ++ct2) {
      float y = (vals[r][ct2] - mn) * inv * w4[ct2] + b4[ct2];
      const size_t idx = (size_t)row * 128 + ch * 64 + ct2 * 16 + lo16;
      hf[idx] = y;
      u16 hb, lb;
      bsplit(y, hb, lb);
      hhi[idx] = hb;
      hlo[idx] = lb;
    }
  }
}

// ---------------- flash attention: 512 threads / 128 q-rows per block,
//                  K/V staged once for 8 waves, P bf16-hi only, o hi-only out ----------------
__global__ __launch_bounds__(512)
void k_attn(const u16* __restrict__ qkh, const u16* __restrict__ qkl,
            const u16* __restrict__ vth, const u16* __restrict__ vtl,
            u16* __restrict__ ohi) {
  __shared__ u16 lK[2][2][64 * 32];
  __shared__ u16 lV[2][2][32 * 64];
  __shared__ u16 lP[8][16 * 72];

  const int tid = threadIdx.x;
  const int wv = tid >> 6, lane = tid & 63;
  const int lo16 = lane & 15, hi2 = lane >> 4;
  const int bid = blockIdx.x;          // 0..511
  const int xcd = bid & 7, g = bid >> 3;
  const int bh = xcd * 8 + (g & 7);
  const int qp = g >> 3;               // 0..7: 128-row q block
  const int b = bh >> 2, h = bh & 3;
  const int st256 = tid & 255;
  const int ar = st256 >> 2, slot = st256 & 3;
  const int kac = ((slot ^ SWZ(ar)) * 8);
  const int kdst = ar * 32 + slot * 8;
  const int vrow = st256 >> 3, vslot = st256 & 7;
  const int vac = ((vslot ^ (vrow & 7)) * 8);
  const bool isK = tid < 256;

  const int qrow = qp * 128 + wv * 16 + lo16;
  const size_t qoff = ((size_t)b * T_ + qrow) * 384 + h * 32 + hi2 * 8;
  bf16x8 qf0 = *(const bf16x8*)&qkh[qoff];
  bf16x8 qf1 = *(const bf16x8*)&qkl[qoff];

  bf16x8 onesf;
#pragma unroll
  for (int j = 0; j < 8; ++j) onesf[j] = (short)0x3F80;

  auto stage = [&](int buf, int kt) {
    if (isK) {
      const size_t krow0 = (size_t)b * T_ + kt * 64;
      gload16(qkh + (krow0 + ar) * 384 + 128 + h * 32 + kac, &lK[buf][0][kdst]);
      gload16(qkl + (krow0 + ar) * 384 + 128 + h * 32 + kac, &lK[buf][1][kdst]);
    } else {
      const size_t vsrc = ((size_t)bh * 32 + vrow) * T_ + kt * 64 + vac;
      gload16(vth + vsrc, &lV[buf][0][vrow * 64 + vslot * 8]);
      gload16(vtl + vsrc, &lV[buf][1][vrow * 64 + vslot * 8]);
    }
  };

  u16* lPp = &lP[wv][0];
  f32x4 oacc[2];
  oacc[0] = (f32x4){0.f, 0.f, 0.f, 0.f};
  oacc[1] = (f32x4){0.f, 0.f, 0.f, 0.f};
  f32x4 lracc = (f32x4){0.f, 0.f, 0.f, 0.f};
  const float cs = 0.17677669529663687f * LOG2E;
  const int kso = ((hi2 ^ SWZ(lo16)) * 8);

  stage(0, 0);
  asm volatile("s_waitcnt vmcnt(0)" ::: "memory");
  __builtin_amdgcn_s_barrier();

  for (int kt = 0; kt < 16; ++kt) {
    const int cur = kt & 1;
    if (kt < 15) stage(cur ^ 1, kt + 1);

    f32x4 s[4];
#pragma unroll
    for (int ct = 0; ct < 4; ++ct) {
      bf16x8 kf0 = *(const bf16x8*)&lK[cur][0][(ct * 16 + lo16) * 32 + kso];
      bf16x8 kf1 = *(const bf16x8*)&lK[cur][1][(ct * 16 + lo16) * 32 + kso];
      f32x4 z = (f32x4){0.f, 0.f, 0.f, 0.f};
      z = mfma_bf16(qf0, kf0, z);
      z = mfma_bf16(qf0, kf1, z);
      z = mfma_bf16(qf1, kf0, z);
      s[ct] = z;
    }
#pragma unroll
    for (int r = 0; r < 4; ++r) {
      float p0 = fexp2(s[0][r] * cs), p1 = fexp2(s[1][r] * cs);
      float p2 = fexp2(s[2][r] * cs), p3 = fexp2(s[3][r] * cs);
      const int prow = hi2 * 4 + r;
      lPp[prow * 72 + 0 * 16 + lo16] = bhi(p0);
      lPp[prow * 72 + 1 * 16 + lo16] = bhi(p1);
      lPp[prow * 72 + 2 * 16 + lo16] = bhi(p2);
      lPp[prow * 72 + 3 * 16 + lo16] = bhi(p3);
    }
    asm volatile("s_waitcnt lgkmcnt(0)" ::: "memory");
    __builtin_amdgcn_sched_barrier(0);
#pragma unroll
    for (int c = 0; c < 2; ++c) {
      bf16x8 ph = *(const bf16x8*)&lPp[lo16 * 72 + c * 32 + hi2 * 8];
      lracc = mfma_bf16(ph, onesf, lracc);
#pragma unroll
      for (int ct2 = 0; ct2 < 2; ++ct2) {
        const int d = ct2 * 16 + lo16;
        const int vso = (((c * 4 + hi2) ^ (lo16 & 7)) * 8);
        bf16x8 vf0 = *(const bf16x8*)&lV[cur][0][d * 64 + vso];
        bf16x8 vf1 = *(const bf16x8*)&lV[cur][1][d * 64 + vso];
        oacc[ct2] = mfma_bf16(ph, vf0, oacc[ct2]);
        oacc[ct2] = mfma_bf16(ph, vf1, oacc[ct2]);
      }
    }
    if (kt < 15) {
      asm volatile("s_waitcnt vmcnt(0)" ::: "memory");
      __builtin_amdgcn_s_barrier();
    }
  }
#pragma unroll
  for (int ct2 = 0; ct2 < 2; ++ct2)
#pragma unroll
    for (int r = 0; r < 4; ++r) {
      float v = oacc[ct2][r] * __builtin_amdgcn_rcpf(lracc[r]);
      const int t = qp * 128 + wv * 16 + hi2 * 4 + r;
      const size_t idx = ((size_t)b * T_ + t) * D_ + h * 32 + ct2 * 16 + lo16;
      ohi[idx] = bhi(v);            // hi-only: out-proj A is single-plane
    }
}

// ---------------- head: final LN -> h out, cosine logits -> probs + GRU gi precompute ----------------
__global__ __launch_bounds__(256)
void k_head(const float* __restrict__ hin, const float* __restrict__ w,
            const float* __restrict__ bws, const float* __restrict__ cn,
            const float* __restrict__ temp,
            const float* __restrict__ wih, const float* __restrict__ bih,
            const float* __restrict__ bhh,
            float4* __restrict__ g4, float* __restrict__ out) {
  const int row = blockIdx.x * 4 + (threadIdx.x >> 6);
  const int lane = threadIdx.x & 63;
  const size_t base = (size_t)row * D_ + lane * 2;
  float2 x = *(const float2*)(hin + base);
  float s = x.x + x.y;
#pragma unroll
  for (int d2 = 1; d2 < 64; d2 <<= 1) s += __shfl_xor(s, d2, 64);
  float m = s * (1.f / 128.f);
  float dx = x.x - m, dy = x.y - m;
  float q = dx * dx + dy * dy;
#pragma unroll
  for (int d2 = 1; d2 < 64; d2 <<= 1) q += __shfl_xor(q, d2, 64);
  float inv = rsqrtf(q * (1.f / 128.f) + 1e-5f);
  float2 ww = *(const float2*)(w + lane * 2);
  float2 bb = *(const float2*)(bws + lane * 2);
  float y0 = dx * inv * ww.x + bb.x;
  float y1 = dy * inv * ww.y + bb.y;
  float2 yo; yo.x = y0; yo.y = y1;
  *(float2*)(out + OUT_H + base) = yo;
  float ss = y0 * y0 + y1 * y1;
#pragma unroll
  for (int d2 = 1; d2 < 64; d2 <<= 1) ss += __shfl_xor(ss, d2, 64);
  float nrm = fmaxf(sqrtf(ss), 1e-12f);
  float z0 = y0 / nrm, z1 = y1 / nrm;
  float lg[4];
#pragma unroll
  for (int rr = 0; rr < 4; ++rr)
    lg[rr] = z0 * cn[rr * 128 + lane * 2] + z1 * cn[rr * 128 + lane * 2 + 1];
#pragma unroll
  for (int d2 = 1; d2 < 64; d2 <<= 1) {
#pragma unroll
    for (int rr = 0; rr < 4; ++rr) lg[rr] += __shfl_xor(lg[rr], d2, 64);
  }
  float ts = 1.f / fmaxf(temp[0], 1e-4f);
#pragma unroll
  for (int rr = 0; rr < 4; ++rr) lg[rr] *= ts;
  float mx = fmaxf(fmaxf(lg[0], lg[1]), fmaxf(lg[2], lg[3]));
  float e0 = __expf(lg[0] - mx), e1 = __expf(lg[1] - mx);
  float e2 = __expf(lg[2] - mx), e3 = __expf(lg[3] - mx);
  float es = e0 + e1 + e2 + e3;
  float einv = 1.f / es;
  float p0 = e0 * einv, p1 = e1 * einv, p2 = e2 * einv, p3 = e3 * einv;
  if (lane < 4) {
    float pr = (lane == 0) ? p0 : (lane == 1) ? p1 : (lane == 2) ? p2 : p3;
    out[OUT_PROBS + (size_t)row * 4 + lane] = pr;
    float gi[3];
#pragma unroll
    for (int g = 0; g < 3; ++g) {
      const float* wr = wih + (g * 4 + lane) * 4;
      gi[g] = bih[g * 4 + lane] + wr[0] * p0 + wr[1] * p1 + wr[2] * p2 + wr[3] * p3;
    }
    const int b = row >> 10, t = row & 1023;
    float4 o4;
    o4.x = -LOG2E * (gi[0] + bhh[0 * 4 + lane]);
    o4.y = -LOG2E * (gi[1] + bhh[1 * 4 + lane]);
    o4.z = 2.f * LOG2E * gi[2];
    o4.w = pr;
    g4[(size_t)t * 64 + b * 4 + lane] = o4;
  }
}

// ---------------- speculative parallel GRU scan, 16 chunks of 64, 128-step warmup ----------------
// warmup error <= ~0.9^128 * |init spread| ~ 1e-6 << existing 1e-2 bf16 floor
__global__ __launch_bounds__(512)
void k_scan(const float4* __restrict__ g4, const float* __restrict__ init,
            const float* __restrict__ whh, const float* __restrict__ bhh,
            float* __restrict__ out) {
  __shared__ float sbuf[4][2][32][64];
  const int tid = threadIdx.x;
  const int wave = tid >> 6, lane = tid & 63;
  const int blk = blockIdx.x;                 // 0..3

  if (wave < 4) {
    __builtin_amdgcn_s_setprio(1);
    const int ci = blk * 4 + wave;            // chunk 0..15
    const int t0 = ci * 64;
    const int start = (t0 >= 128) ? (t0 - 128) : 0;
    const int nwarm = (t0 - start) >> 5;
    const int r = lane & 3;
    const float sc[3] = {-LOG2E, -LOG2E, 2.f * LOG2E};
    float Wh[3][4];
#pragma unroll
    for (int g = 0; g < 3; ++g)
#pragma unroll
      for (int j = 0; j < 4; ++j) Wh[g][j] = whh[(g * 4 + r) * 4 + j] * sc[g];
    const float Bh2 = bhh[2 * 4 + r] * (2.f * LOG2E);
    float st = init[lane];

    const float4* gp = g4 + (size_t)start * 64 + lane;
    const float4* gpre = gp + 8 * 64;
    float4 pre[8];
#pragma unroll
    for (int d = 0; d < 8; ++d) pre[d] = gp[d * 64];

    auto do32 = [&](float* dstbuf) {
      for (int u = 0; u < 4; ++u) {
#pragma unroll
        for (int d = 0; d < 8; ++d) {
          float4 v = pre[d];
          pre[d] = gpre[d * 64];
          const float stm1 = st - 1.f;
          float s0 = qb0(st), s1 = qb1(st), s2 = qb2(st), s3 = qb3(st);
          float ar0 = fmaf(Wh[0][1], s1, fmaf(Wh[0][0], s0, v.x));
          float ar1 = fmaf(Wh[0][3], s3, Wh[0][2] * s2);
          float a_r = ar0 + ar1;
          float az0 = fmaf(Wh[1][1], s1, fmaf(Wh[1][0], s0, v.y));
          float az1 = fmaf(Wh[1][3], s3, Wh[1][2] * s2);
          float a_z = az0 + az1;
          float an0 = fmaf(Wh[2][1], s1, fmaf(Wh[2][0], s0, Bh2));
          float an1 = fmaf(Wh[2][3], s3, Wh[2][2] * s2);
          float g_n = an0 + an1;
          float rg = __builtin_amdgcn_rcpf(1.f + fexp2(a_r));
          float zg = __builtin_amdgcn_rcpf(1.f + fexp2(a_z));
          float zg09 = 0.9f * zg;
          float nxp = fmaf(rg, g_n, v.z);
          float rcpv = __builtin_amdgcn_rcpf(1.f + fexp2(nxp));
          float ng09 = fmaf(-1.8f, rcpv, 0.9f);
          float stmn = fmaf(2.f, rcpv, stm1);
          float base2 = fmaf(0.1f, v.w, ng09);
          float sn = fmaf(zg09, stmn, base2);
          st = sn;
          if (dstbuf) dstbuf[(u * 8 + d) * 64 + lane] = sn;
        }
        gpre += 8 * 64;
      }
    };

    for (int c = 0; c < nwarm; ++c) do32(nullptr);
    for (int s = 0; s < 3; ++s) {
      if (s < 2) do32(&sbuf[wave][s][0][0]);
      __syncthreads();
    }
    if (ci == 15) out[OUT_FS + lane] = st;
  } else {
    const int w2 = wave - 4;
    const int tbase = (blk * 4 + w2) * 64;
    for (int s = 0; s < 3; ++s) {
      if (s >= 1) {
        const float* src = &sbuf[w2][s - 1][0][0];
        const int tb = tbase + (s - 1) * 32;
#pragma unroll
        for (int k = 0; k < 8; ++k) {
          const int linear = k * 64 + lane;
          const int tl = linear & 31, b = linear >> 5;
          float4 v = *(const float4*)&src[tl * 64 + b * 4];
          const int t = tb + tl;
          *(float4*)&out[OUT_SP + (size_t)b * 4096 + t * 4] = v;
          int am = 0; float bv = v.x;
          if (v.y > bv) { bv = v.y; am = 1; }
          if (v.z > bv) { bv = v.z; am = 2; }
          if (v.w > bv) { bv = v.w; am = 3; }
          out[OUT_REG + (size_t)b * 1024 + t] = (float)am;
        }
      }
      __syncthreads();
    }
  }
}

// ---------------- launch ----------------
extern "C" void kernel_launch(void* const* d_in, const int* in_sizes, int n_in,
                              void* d_out, int out_size, void* d_ws, size_t ws_size,
                              hipStream_t stream) {
  (void)in_sizes; (void)n_in; (void)out_size; (void)ws_size;
  const float* x     = (const float*)d_in[0];
  const float* init  = (const float*)d_in[1];
  const float* in_w  = (const float*)d_in[2];
  const float* in_b  = (const float*)d_in[3];
  const float* qkv_w = (const float*)d_in[4];
  const float* qkv_b = (const float*)d_in[5];
  const float* out_w = (const float*)d_in[6];
  const float* out_b = (const float*)d_in[7];
  const float* ln1w  = (const float*)d_in[8];
  const float* ln1b  = (const float*)d_in[9];
  const float* ff1w  = (const float*)d_in[10];
  const float* ff1b  = (const float*)d_in[11];
  const float* ff2w  = (const float*)d_in[12];
  const float* ff2b  = (const float*)d_in[13];
  const float* ln2w  = (const float*)d_in[14];
  const float* ln2b  = (const float*)d_in[15];
  const float* nw    = (const float*)d_in[16];
  const float* nb    = (const float*)d_in[17];
  const float* cent  = (const float*)d_in[18];
  const float* temp  = (const float*)d_in[19];
  const float* gwih  = (const float*)d_in[20];
  const float* gwhh  = (const float*)d_in[21];
  const float* gbih  = (const float*)d_in[22];
  const float* gbhh  = (const float*)d_in[23];
  float* out = (float*)d_out;

  char* wsp = (char*)d_ws;
  auto take = [&](size_t bytes) -> char* {
    char* p = wsp;
    wsp += (bytes + 255) & ~(size_t)255;
    return p;
  };
  u16* xhi = (u16*)take((size_t)1048576 * 2);
  u16* xlo = (u16*)take((size_t)1048576 * 2);
  float* hf = (float*)take((size_t)M_ * 128 * 4);
  u16* hhi = (u16*)take((size_t)M_ * 128 * 2);
  u16* hlo = (u16*)take((size_t)M_ * 128 * 2);
  char* U = take(33554432);                 // union: qkv planes / ff1 planes
  u16* qkvhi = (u16*)U;
  u16* qkvlo = (u16*)(U + 12582912);
  u16* f1hi = (u16*)U;
  u16* f1lo = (u16*)(U + 16777216);
  u16* vthi = (u16*)take((size_t)2097152 * 2);
  u16* vtlo = (u16*)take((size_t)2097152 * 2);
  u16* ohi = (u16*)take((size_t)2097152 * 2);
  u16* olo = (u16*)take((size_t)2097152 * 2);   // unused (o hi-only); kept for layout
  u16* inwhi = (u16*)take(8192 * 2);   u16* inwlo = (u16*)take(8192 * 2);
  u16* qwhi = (u16*)take(196608 * 2);  u16* qwlo = (u16*)take(196608 * 2);
  u16* owhi = (u16*)take(65536 * 2);   u16* owlo = (u16*)take(65536 * 2);
  u16* f1whi = (u16*)take(262144 * 2); u16* f1wlo = (u16*)take(262144 * 2);
  u16* f2whi = (u16*)take(262144 * 2); u16* f2wlo = (u16*)take(262144 * 2);
  float* cnorm = (float*)take(512 * 4);
  float4* g4 = (float4*)take((size_t)(T_ + 8) * 64 * 16);

  k_split6<<<1801, 256, 0, stream>>>(x, xhi, xlo, in_w, inwhi, inwlo,
                                     qkv_w, qwhi, qwlo, out_w, owhi, owlo,
                                     ff1w, f1whi, f1wlo, ff2w, f2whi, f2wlo,
                                     cent, cnorm);

  k_gemm<0, 3, 0><<<dim3(128, 2), 256, 0, stream>>>(xhi, xlo, inwhi, inwlo, in_b,
                                                    hf, hhi, hlo, nullptr, nullptr, 128, 64);

  for (int l = 0; l < 4; ++l) {
    k_gemm<0, 2, 1><<<dim3(128, 6), 256, 0, stream>>>(
        hhi, hlo, qwhi + l * 49152, qwlo + l * 49152, qkv_b + l * 384,
        nullptr, qkvhi, qkvlo, vthi, vtlo, 384, 128);
    k_attn<<<512, 512, 0, stream>>>(qkvhi, qkvlo, vthi, vtlo, ohi);
    k_gemm_ln<4, 1><<<512, 256, 0, stream>>>(
        ohi, olo, owhi + l * 16384, owlo + l * 16384, out_b + l * 128,
        hf, ln1w + l * 128, ln1b + l * 128, hf, hhi, hlo);
    k_gemm<1, 2, 0><<<dim3(128, 8), 256, 0, stream>>>(
        hhi, hlo, f1whi + l * 65536, f1wlo + l * 65536, ff1b + l * 512,
        nullptr, f1hi, f1lo, nullptr, nullptr, 512, 128);
    k_gemm_ln<16, 2><<<512, 256, 0, stream>>>(
        f1hi, f1lo, f2whi + l * 65536, f2wlo + l * 65536, ff2b + l * 128,
        hf, ln2w + l * 128, ln2b + l * 128, hf, hhi, hlo);
  }

  k_head<<<4096, 256, 0, stream>>>(hf, nw, nb, cnorm, temp, gwih, gbih, gbhh, g4, out);
  k_scan<<<4, 512, 0, stream>>>(g4, init, gwhh, gbhh, out);
}